// Round 13
// baseline (910.263 us; speedup 1.0000x reference)
//
#include <hip/hip_runtime.h>
#include <math.h>

#define LL   2048
#define BB   8
#define CC   32
#define CHH  256
#define HH   8
#define DD   6

typedef _Float16 h8 __attribute__((ext_vector_type(8)));
typedef _Float16 h4 __attribute__((ext_vector_type(4)));
typedef float f4 __attribute__((ext_vector_type(4)));
typedef float f2v __attribute__((ext_vector_type(2)));

// ---------------------------------------------------------------- encoder
__global__ __launch_bounds__(256) void k_enc(const float* __restrict__ x,
    const float* __restrict__ W, const float* __restrict__ bias,
    float* __restrict__ X) {
  int idx = blockIdx.x * 256 + threadIdx.x;          // B*32*L = 524288
  int l = idx & (LL - 1);
  int c = (idx >> 11) & 31;
  int b = idx >> 16;
  float s = bias[c];
#pragma unroll
  for (int i = 0; i < 6; ++i)
    s = fmaf(W[c * 6 + i], x[((size_t)b * 6 + i) * LL + l], s);
  X[idx] = s;
}

// ------------- fused QKV: pointwise conv + depthwise conv3/conv15 + gate +
// cvt + layout (R6-verified form). grid (1024 = bh*16+lt, 3 z), 256 thr.
// LDS: Xt f32[32][144] @0 | o_tile 32x304B @18432 | Wt @28160 -> 32384.
__global__ __launch_bounds__(256) void k_qkv(const float* __restrict__ X,
    const float* __restrict__ pwq, const float* __restrict__ pwk,
    const float* __restrict__ pwv,
    const float* __restrict__ d3q, const float* __restrict__ d15q, const float* __restrict__ gq,
    const float* __restrict__ d3k, const float* __restrict__ d15k, const float* __restrict__ gk,
    const float* __restrict__ d3v, const float* __restrict__ d15v, const float* __restrict__ gv,
    _Float16* __restrict__ Qt, _Float16* __restrict__ Kt, _Float16* __restrict__ Vt) {
  __shared__ __align__(16) char lds[32384];
  int z  = blockIdx.y;
  int bx = blockIdx.x;
  int bh = bx >> 4, lt = bx & 15, l0 = lt * 128;
  int b = bh >> 3, h = bh & 7;
  int t = threadIdx.x;
  const float* pwp  = (z == 0) ? pwq  : (z == 1) ? pwk  : pwv;
  const float* w3p  = (z == 0) ? d3q  : (z == 1) ? d3k  : d3v;
  const float* w15p = (z == 0) ? d15q : (z == 1) ? d15k : d15v;
  const float* gp   = (z == 0) ? gq   : (z == 1) ? gk   : gv;

  float* Xt = (float*)lds;                     // [32][144]
  float* Wt = (float*)(lds + 28160);           // Wt[ci*33 + och]

  // ---- stage X tile [32 ci][144 l] (l = l0-8 .. l0+135, OOB zero)
  {
    int r = t >> 3, u = t & 7;
    const float* xr = X + ((size_t)b * CC + r) * LL;
    float* xd = Xt + r * 144;
#pragma unroll
    for (int s = u; s < 36; s += 8) {
      int ls = l0 - 8 + s * 4;
      f4 v;
      if (ls >= 0 && ls + 3 < LL) {
        v = *(const f4*)(xr + ls);
      } else {
#pragma unroll
        for (int e = 0; e < 4; ++e) {
          int l = ls + e;
          v[e] = (l >= 0 && l < LL) ? xr[l] : 0.f;
        }
      }
      *(f4*)(xd + s * 4) = v;
    }
  }
  // ---- stage W transposed: Wt[ci*33 + r] = pwp[(h*32+r)*32 + ci]
  {
    f4 wg = ((const f4*)(pwp + h * 1024))[t];
#pragma unroll
    for (int d2 = 0; d2 < 4; ++d2) {
      int e = t * 4 + d2;
      Wt[(e & 31) * 33 + (e >> 5)] = wg[d2];
    }
  }
  __syncthreads();

  // ---- phase 1: pointwise conv -> o_tile f16
  {
    int r = t & 31, seg = t >> 5;               // 18 l per (r,seg)
    float acc[18];
#pragma unroll
    for (int k = 0; k < 18; ++k) acc[k] = 0.f;
    for (int ci = 0; ci < 32; ++ci) {
      float w = Wt[ci * 33 + r];
      const f2v* X2 = (const f2v*)(Xt + ci * 144 + seg * 18);
#pragma unroll
      for (int m = 0; m < 9; ++m) {
        f2v xv = X2[m];
        acc[2 * m]     = fmaf(w, xv[0], acc[2 * m]);
        acc[2 * m + 1] = fmaf(w, xv[1], acc[2 * m + 1]);
      }
    }
    unsigned* orow = (unsigned*)(lds + 18432 + r * 304 + seg * 36);
#pragma unroll
    for (int m = 0; m < 9; ++m)
      orow[m] = __builtin_bit_cast(unsigned,
          __builtin_amdgcn_cvt_pkrtz(acc[2 * m], acc[2 * m + 1]));
  }
  __syncthreads();

  // ---- phase 2: depthwise conv3 + conv15 + softmax gate
  int c = t & 31, cg = t >> 5;
  float wv[32];
  {
    const h8* wp = (const h8*)(lds + 18432 + c * 304 + cg * 32);
#pragma unroll
    for (int q4 = 0; q4 < 4; ++q4) {
      h8 v = wp[q4];
#pragma unroll
      for (int e = 0; e < 8; ++e) wv[q4 * 8 + e] = (float)v[e];
    }
  }
  float r0 = gp[0], r1 = gp[1];
  float mx = fmaxf(r0, r1);
  float e0 = __expf(r0 - mx), e1 = __expf(r1 - mx);
  float gi = 1.f / (e0 + e1);
  float g0 = e0 * gi, g1 = e1 * gi;
  float sc = (z == 0) ? 0.2550765737f : 1.0f;   // C^-0.5 * log2(e) fold
  int ch = h * 32 + c;
  float w3r[3], w15r[15];
#pragma unroll
  for (int k = 0; k < 3; ++k)  w3r[k]  = w3p[ch * 3 + k];
#pragma unroll
  for (int k = 0; k < 15; ++k) w15r[k] = w15p[ch * 15 + k];

  h8 olo, ohi;
#pragma unroll
  for (int i = 0; i < 16; ++i) {
    float a = 0.f;
#pragma unroll
    for (int k = 0; k < 3; ++k) a = fmaf(w3r[k], wv[i + 7 + k], a);
    float s15 = 0.f;
#pragma unroll
    for (int k = 0; k < 15; ++k) s15 = fmaf(w15r[k], wv[i + 1 + k], s15);
    float val = (g0 * a + g1 * s15) * sc;
    if (i < 8) olo[i] = (_Float16)val; else ohi[i - 8] = (_Float16)val;
  }

  if (z == 2) {
    _Float16* dst = Vt + ((size_t)bh * 32 + c) * LL + l0 + cg * 16;
    *(h8*)dst = olo;
    *(h8*)(dst + 8) = ohi;
  } else {
    char* ot = lds;                             // reuse Xt region (dead)
#pragma unroll
    for (int i = 0; i < 16; ++i) {
      _Float16 v = (i < 8) ? olo[i] : ohi[i - 8];
      *(_Float16*)(ot + (cg * 16 + i) * 80 + c * 2) = v;
    }
    __syncthreads();
    _Float16* dst = ((z == 0) ? Qt : Kt) + ((size_t)bh * LL + l0) * 32;
    int l = t >> 1, hf = t & 1;
    uint4 a = *(uint4*)(ot + l * 80 + hf * 32);
    uint4 b2 = *(uint4*)(ot + l * 80 + hf * 32 + 16);
    *(uint4*)(dst + (size_t)l * 32 + hf * 16) = a;
    *(uint4*)(dst + (size_t)l * 32 + hf * 16 + 8) = b2;
  }
}

// ------------------------------------------------ MFMA flash attention (f16)
// R13: epilogue writes AO in [b][l][256ch] layout (h4 stores) so k_uni_res
// reads contiguous-per-thread. Everything else = R4/R6 verified form.
__global__ __launch_bounds__(512, 2) void k_attn(
    const _Float16* __restrict__ Qt, const _Float16* __restrict__ Kt,
    const _Float16* __restrict__ Vt, _Float16* __restrict__ AO) {
  __shared__ __align__(16) char lds[38912];
  const int tid  = threadIdx.x;
  const int lane = tid & 63;
  const int w    = tid >> 6;                   // 0..7
  const int seg  = w >> 2;                     // 0..1: key segment
  const int wq   = w & 3;                      // q sub-block within 128
  const int g    = lane >> 4;
  const int ln   = lane & 15;
  const int h2c  = (wq >> 1) * 2;
  const int qb   = blockIdx.x;                 // 0..15
  const int bh   = blockIdx.y;                 // 0..63
  const _Float16* Qg = Qt + ((size_t)bh * LL + qb * 128) * 32;
  const _Float16* Kg = Kt + ((size_t)bh * LL + seg * 1024) * 32;
  const _Float16* Vg = Vt + (size_t)bh * 32 * LL + seg * 1024;

  h8 qf[2];
#pragma unroll
  for (int nt = 0; nt < 2; ++nt)
    qf[nt] = *(const h8*)(Qg + (size_t)(wq * 32 + nt * 16 + ln) * 32 + g * 8);

  h8 ones;
#pragma unroll
  for (int j = 0; j < 8; ++j) ones[j] = (_Float16)1.0f;

  char* kb = lds + seg * 5120;                 // + p*10240
  char* vb = lds + 20480 + seg * 4608;         // + p*9216

  uint4 stg0, stg1;
  if ((wq & 1) == 0) {
    const uint4* gk = (const uint4*)Kg;
    stg0 = gk[h2c * 64 + lane];
    stg1 = gk[(h2c + 1) * 64 + lane];
    *(uint4*)(kb + (h2c * 16 + (lane >> 2)) * 80 + (lane & 3) * 16) = stg0;
    *(uint4*)(kb + ((h2c + 1) * 16 + (lane >> 2)) * 80 + (lane & 3) * 16) = stg1;
  } else {
    int c0 = h2c * 8 + (lane >> 3);
    stg0 = *(const uint4*)(Vg + (size_t)c0 * LL + (lane & 7) * 8);
    stg1 = *(const uint4*)(Vg + (size_t)(c0 + 8) * LL + (lane & 7) * 8);
    *(uint4*)(vb + c0 * 144 + (lane & 7) * 16) = stg0;
    *(uint4*)(vb + (c0 + 8) * 144 + (lane & 7) * 16) = stg1;
  }
  __syncthreads();

  f4 o[2][2];
#pragma unroll
  for (int ct = 0; ct < 2; ++ct)
#pragma unroll
    for (int nt = 0; nt < 2; ++nt) o[ct][nt] = (f4){0.f, 0.f, 0.f, 0.f};
  f4 sacc[2];
#pragma unroll
  for (int nt = 0; nt < 2; ++nt) sacc[nt] = (f4){0.f, 0.f, 0.f, 0.f};

  for (int it = 0; it < 16; ++it) {
    int pp = it & 1;
    char* kbc = kb + pp * 10240;
    char* vbc = vb + pp * 9216;
    if (it < 15) {
      int k0n = (it + 1) * 64;
      if ((wq & 1) == 0) {
        const uint4* gk = (const uint4*)(Kg + (size_t)k0n * 32);
        stg0 = gk[h2c * 64 + lane];
        stg1 = gk[(h2c + 1) * 64 + lane];
      } else {
        int c0 = h2c * 8 + (lane >> 3);
        stg0 = *(const uint4*)(Vg + (size_t)c0 * LL + k0n + (lane & 7) * 8);
        stg1 = *(const uint4*)(Vg + (size_t)(c0 + 8) * LL + k0n + (lane & 7) * 8);
      }
    }
#pragma unroll
    for (int chunk = 0; chunk < 2; ++chunk) {
      unsigned pa[2][2], pb[2][2];
#pragma unroll
      for (int mt2 = 0; mt2 < 2; ++mt2) {
        h8 kf = *(const h8*)(kbc + ((chunk * 2 + mt2) * 16 + ln) * 80 + g * 16);
#pragma unroll
        for (int nt = 0; nt < 2; ++nt) {
          f4 z = {0.f, 0.f, 0.f, 0.f};
          f4 s = __builtin_amdgcn_mfma_f32_16x16x32_f16(kf, qf[nt], z, 0, 0, 0);
          float p0 = __builtin_amdgcn_exp2f(s[0]);
          float p1 = __builtin_amdgcn_exp2f(s[1]);
          float p2 = __builtin_amdgcn_exp2f(s[2]);
          float p3 = __builtin_amdgcn_exp2f(s[3]);
          unsigned lo = __builtin_bit_cast(unsigned,
              __builtin_amdgcn_cvt_pkrtz(p0, p1));
          unsigned hi = __builtin_bit_cast(unsigned,
              __builtin_amdgcn_cvt_pkrtz(p2, p3));
          if (mt2 == 0) { pa[nt][0] = lo; pa[nt][1] = hi; }
          else          { pb[nt][0] = lo; pb[nt][1] = hi; }
        }
      }
      h8 vf[2];
#pragma unroll
      for (int ct = 0; ct < 2; ++ct)
        vf[ct] = *(const h8*)(vbc + (ct * 16 + ln) * 144 + chunk * 64 + g * 16);
#pragma unroll
      for (int nt = 0; nt < 2; ++nt) {
        unsigned w0 = pa[nt][0], w1 = pa[nt][1];
        unsigned w2 = pb[nt][0], w3 = pb[nt][1];
        asm("v_permlane32_swap_b32 %0, %1" : "+v"(w0), "+v"(w2));
        asm("v_permlane16_swap_b32 %0, %1" : "+v"(w0), "+v"(w2));
        asm("v_permlane32_swap_b32 %0, %1" : "+v"(w1), "+v"(w3));
        asm("v_permlane16_swap_b32 %0, %1" : "+v"(w1), "+v"(w3));
        uint4 pw4; pw4.x = w0; pw4.y = w1; pw4.z = w2; pw4.w = w3;
        h8 pf = __builtin_bit_cast(h8, pw4);
        sacc[nt] = __builtin_amdgcn_mfma_f32_16x16x32_f16(ones, pf, sacc[nt], 0, 0, 0);
        o[0][nt] = __builtin_amdgcn_mfma_f32_16x16x32_f16(vf[0], pf, o[0][nt], 0, 0, 0);
        o[1][nt] = __builtin_amdgcn_mfma_f32_16x16x32_f16(vf[1], pf, o[1][nt], 0, 0, 0);
      }
    }
    if (it < 15) {
      char* kbn = kb + (pp ^ 1) * 10240;
      char* vbn = vb + (pp ^ 1) * 9216;
      if ((wq & 1) == 0) {
        *(uint4*)(kbn + (h2c * 16 + (lane >> 2)) * 80 + (lane & 3) * 16) = stg0;
        *(uint4*)(kbn + ((h2c + 1) * 16 + (lane >> 2)) * 80 + (lane & 3) * 16) = stg1;
      } else {
        int c0 = h2c * 8 + (lane >> 3);
        *(uint4*)(vbn + c0 * 144 + (lane & 7) * 16) = stg0;
        *(uint4*)(vbn + (c0 + 8) * 144 + (lane & 7) * 16) = stg1;
      }
    }
    __syncthreads();
  }

  if (seg == 1) {
    char* eo = lds + wq * 9216 + lane * 144;
#pragma unroll
    for (int nt = 0; nt < 2; ++nt)
#pragma unroll
      for (int ct = 0; ct < 2; ++ct)
        *(f4*)(eo + (nt * 2 + ct) * 16) = o[ct][nt];
    f4 sv;
    sv[0] = sacc[0][0]; sv[1] = sacc[1][0];
    sv[2] = 0.f; sv[3] = 0.f;
    *(f4*)(eo + 64) = sv;
  }
  __syncthreads();
  if (seg == 0) {
    const char* po = lds + wq * 9216 + lane * 144;
    f4 s1v = *(const f4*)(po + 64);
    // AO [b][l][256ch]: base + (b*LL + qg)*256 + h*32 + c, c = ct*16 + g*4 + r
    _Float16* out = AO + ((size_t)(bh >> 3) * LL) * 256 + (bh & 7) * 32 + g * 4;
#pragma unroll
    for (int nt = 0; nt < 2; ++nt) {
      float inv = 1.f / (sacc[nt][0] + s1v[nt]);
      int qg = qb * 128 + wq * 32 + nt * 16 + ln;
      _Float16* op = out + (size_t)qg * 256;
#pragma unroll
      for (int ct = 0; ct < 2; ++ct) {
        f4 o1 = *(const f4*)(po + (nt * 2 + ct) * 16);
        h4 hv;
#pragma unroll
        for (int r = 0; r < 4; ++r)
          hv[r] = (_Float16)((o[ct][nt][r] + o1[r]) * inv);
        *(h4*)(op + ct * 16) = hv;
      }
    }
  }
}

// -------- uni GEMM [32,256] f16-in + bias + residual, v4.
// R13: AO now [b][l][256ch] -> per thread the 64 cc values are contiguous:
// 8 x h8 vector loads replace 64 scalar stride-4KB loads (8x fewer issues,
// same bytes, same accumulation order). W reads unchanged (R11 lesson: they
// pipeline fine). grid 512 (8b x 32lt x 2half), 64 l per block, cc-split 4.
__global__ __launch_bounds__(256) void k_uni_res(const _Float16* __restrict__ AO,
    const float* __restrict__ W, const float* __restrict__ bias,
    const float* __restrict__ Xin, float* __restrict__ Y) {
  __shared__ float ps[3][64 * 17];
  int t    = threadIdx.x;
  int li   = t & 63;
  int cg   = t >> 6;                            // 0..3: cc quarter
  int bx   = blockIdx.x;                        // 512 blocks
  int lt   = bx & 31;
  int half = (bx >> 5) & 1;
  int b    = bx >> 6;
  int l    = lt * 64 + li;
  const _Float16* ap = AO + ((size_t)b * LL + l) * 256 + cg * 64;
  float acc[16];
#pragma unroll
  for (int j = 0; j < 16; ++j) acc[j] = 0.f;
  for (int c8 = 0; c8 < 8; ++c8) {
    h8 av = *(const h8*)(ap + c8 * 8);
    float a[8];
#pragma unroll
    for (int e = 0; e < 8; ++e) a[e] = (float)av[e];
#pragma unroll
    for (int j = 0; j < 16; ++j) {
      const float* wr = W + (half * 16 + j) * CHH + cg * 64 + c8 * 8;
#pragma unroll
      for (int e = 0; e < 8; ++e)
        acc[j] = fmaf(wr[e], a[e], acc[j]);
    }
  }
  if (cg) {
#pragma unroll
    for (int j = 0; j < 16; ++j) ps[cg - 1][li * 17 + j] = acc[j];
  }
  __syncthreads();
  if (!cg) {
#pragma unroll
    for (int j = 0; j < 16; ++j) {
      int c = half * 16 + j;
      size_t o = ((size_t)b * CC + c) * LL + l;
      Y[o] = acc[j] + ps[0][li * 17 + j] + ps[1][li * 17 + j] +
             ps[2][li * 17 + j] + bias[c] + Xin[o];
    }
  }
}

// ---------------------------------------------------------- instance norm
// (R10-verified form: 512 threads, 4 elems/thread scalar — R12's f4 variant
// was null-to-negative; inorm is launch/latency-structural.)
__global__ __launch_bounds__(512) void k_inorm(const float* __restrict__ Y,
    float* __restrict__ X, const float* __restrict__ g,
    const float* __restrict__ bt) {
  __shared__ float red[16];
  int row = blockIdx.x;
  int c = row & 31;
  const float* y = Y + (size_t)row * LL;
  float v[4];
  float s = 0.f, ss = 0.f;
#pragma unroll
  for (int i = 0; i < 4; ++i) {
    v[i] = y[threadIdx.x + 512 * i];
    s += v[i];
    ss = fmaf(v[i], v[i], ss);
  }
#pragma unroll
  for (int off = 32; off; off >>= 1) {
    s  += __shfl_down(s, off);
    ss += __shfl_down(ss, off);
  }
  int wid = threadIdx.x >> 6;
  if ((threadIdx.x & 63) == 0) { red[wid * 2] = s; red[wid * 2 + 1] = ss; }
  __syncthreads();
  if (threadIdx.x == 0) {
    float rs0 = 0.f, rs1 = 0.f;
#pragma unroll
    for (int i = 0; i < 8; ++i) { rs0 += red[i * 2]; rs1 += red[i * 2 + 1]; }
    red[0] = rs0; red[1] = rs1;
  }
  __syncthreads();
  float mean = red[0] * (1.f / LL);
  float var  = red[1] * (1.f / LL) - mean * mean;
  float rs = rsqrtf(var + 1e-5f) * g[c];
  float bb = bt[c];
#pragma unroll
  for (int i = 0; i < 4; ++i)
    X[(size_t)row * LL + threadIdx.x + 512 * i] = (v[i] - mean) * rs + bb;
}

// -------- fused FFN v5 (R10-verified): LDS-staged weights, phase-split.
// LDS: wlds 33.3KB + ps 29.6KB = 62.8KB -> 2 blocks/CU.
__global__ __launch_bounds__(256) void k_ffn(const float* __restrict__ X,
    const float* __restrict__ W1, const float* __restrict__ b1,
    const float* __restrict__ W2, const float* __restrict__ b2,
    float* __restrict__ Y) {
  __shared__ __align__(16) float wlds[8320];    // W1 @0, W2 @4096, b1 @8192
  __shared__ float ps[7][32 * 33];
  int bx = blockIdx.x;                          // 8b * 64lt
  int b = bx >> 6;
  int l0 = (bx & 63) * 32;
  int t = threadIdx.x;
  int li = t & 31;
  int og = t >> 5;                              // 0..7
  int l = l0 + li;
  // ---- stage weights to LDS (coalesced f4)
#pragma unroll
  for (int i = 0; i < 4; ++i)
    ((f4*)wlds)[t + i * 256] = ((const f4*)W1)[t + i * 256];
#pragma unroll
  for (int i = 0; i < 4; ++i)
    ((f4*)(wlds + 4096))[t + i * 256] = ((const f4*)W2)[t + i * 256];
  if (t < 32) ((f4*)(wlds + 8192))[t] = ((const f4*)b1)[t];

  const float* Xp = X + (size_t)b * CC * LL + l;
  float xv[32];
#pragma unroll
  for (int c = 0; c < 32; ++c) xv[c] = Xp[(size_t)c * LL];
  __syncthreads();

  // ---- phase A: 16 hidden units, 4-wide partial chains from LDS
  float hs[16];
#pragma unroll
  for (int op = 0; op < 16; ++op) {
    int o = og * 16 + op;
    const f4* wr = (const f4*)(wlds + o * 32);
    f4 p = {wlds[8192 + o], 0.f, 0.f, 0.f};
#pragma unroll
    for (int c4 = 0; c4 < 8; ++c4) {
      f4 a = wr[c4];
      p[0] = fmaf(a[0], xv[c4 * 4 + 0], p[0]);
      p[1] = fmaf(a[1], xv[c4 * 4 + 1], p[1]);
      p[2] = fmaf(a[2], xv[c4 * 4 + 2], p[2]);
      p[3] = fmaf(a[3], xv[c4 * 4 + 3], p[3]);
    }
    hs[op] = fmaxf((p[0] + p[1]) + (p[2] + p[3]), 0.f);
  }

  // ---- phase B: 32 outputs, f4 W2 reads from LDS
  float acc[32];
#pragma unroll
  for (int c = 0; c < 32; ++c) {
    const f4* w2r = (const f4*)(wlds + 4096 + c * 128 + og * 16);
    f4 s = {0.f, 0.f, 0.f, 0.f};
#pragma unroll
    for (int o4 = 0; o4 < 4; ++o4) {
      f4 w = w2r[o4];
      s[0] = fmaf(w[0], hs[o4 * 4 + 0], s[0]);
      s[1] = fmaf(w[1], hs[o4 * 4 + 1], s[1]);
      s[2] = fmaf(w[2], hs[o4 * 4 + 2], s[2]);
      s[3] = fmaf(w[3], hs[o4 * 4 + 3], s[3]);
    }
    acc[c] = (s[0] + s[1]) + (s[2] + s[3]);
  }

  if (og) {
#pragma unroll
    for (int c = 0; c < 32; ++c) ps[og - 1][li * 33 + c] = acc[c];
  }
  __syncthreads();
  if (!og) {
    float* Yp = Y + (size_t)b * CC * LL + l;
#pragma unroll
    for (int c = 0; c < 32; ++c) {
      float r = acc[c] + b2[c] + xv[c];
#pragma unroll
      for (int q = 0; q < 7; ++q) r += ps[q][li * 33 + c];
      Yp[(size_t)c * LL] = r;
    }
  }
}

// ------------------------------------------------------------- classifier
__global__ __launch_bounds__(256) void k_cls(const float* __restrict__ X,
    const float* __restrict__ W, const float* __restrict__ bias,
    float* __restrict__ out) {
  int idx = blockIdx.x * 256 + threadIdx.x;
  int l = idx & (LL - 1);
  int b = idx >> 11;
  float s = bias[0];
#pragma unroll
  for (int c = 0; c < CC; ++c)
    s = fmaf(W[c], X[((size_t)b * CC + c) * LL + l], s);
  out[idx] = 1.f / (1.f + __expf(-s));
}

// ------------------------------------------------------------------ launch
extern "C" void kernel_launch(void* const* d_in, const int* in_sizes, int n_in,
                              void* d_out, int out_size, void* d_ws,
                              size_t ws_size, hipStream_t stream) {
  const float* x      = (const float*)d_in[0];
  const float* enc_W  = (const float*)d_in[1];
  const float* enc_b  = (const float*)d_in[2];
  const float* pw_q   = (const float*)d_in[3];
  const float* dw3_q  = (const float*)d_in[4];
  const float* dw15_q = (const float*)d_in[5];
  const float* gate_q = (const float*)d_in[6];
  const float* pw_k   = (const float*)d_in[7];
  const float* dw3_k  = (const float*)d_in[8];
  const float* dw15_k = (const float*)d_in[9];
  const float* gate_k = (const float*)d_in[10];
  const float* pw_v   = (const float*)d_in[11];
  const float* dw3_v  = (const float*)d_in[12];
  const float* dw15_v = (const float*)d_in[13];
  const float* gate_v = (const float*)d_in[14];
  const float* uni_W  = (const float*)d_in[15];
  const float* uni_b  = (const float*)d_in[16];
  const float* n1_g   = (const float*)d_in[17];
  const float* n1_b   = (const float*)d_in[18];
  const float* n2_g   = (const float*)d_in[19];
  const float* n2_b   = (const float*)d_in[20];
  const float* ffn_W1 = (const float*)d_in[21];
  const float* ffn_b1 = (const float*)d_in[22];
  const float* ffn_W2 = (const float*)d_in[23];
  const float* ffn_b2 = (const float*)d_in[24];
  const float* cls_W  = (const float*)d_in[25];
  const float* cls_b  = (const float*)d_in[26];

  float* ws = (float*)d_ws;
  float* X   = ws;                             // [B,32,L] fp32
  float* Y   = ws + 524288;                    // [B,32,L] fp32
  _Float16* AO = (_Float16*)(ws + 1048576);    // [B,L,256] f16 attn out
  _Float16* Qt = (_Float16*)(ws + 9437184);    // [64bh][L][32c] f16
  _Float16* Kt = (_Float16*)(ws + 11534336);   // [64bh][L][32c] f16
  _Float16* Vt = (_Float16*)(ws + 13631488);   // [64bh][32c][L] f16

  k_enc<<<2048, 256, 0, stream>>>(x, enc_W, enc_b, X);

  for (int d = 0; d < DD; ++d) {
    k_qkv<<<dim3(1024, 3), 256, 0, stream>>>(X,
        pw_q + d * CHH * CC, pw_k + d * CHH * CC, pw_v + d * CHH * CC,
        dw3_q + d * CHH * 3, dw15_q + d * CHH * 15, gate_q + d * 2,
        dw3_k + d * CHH * 3, dw15_k + d * CHH * 15, gate_k + d * 2,
        dw3_v + d * CHH * 3, dw15_v + d * CHH * 15, gate_v + d * 2,
        Qt, Kt, Vt);
    k_attn<<<dim3(16, 64), 512, 0, stream>>>(Qt, Kt, Vt, AO);
    k_uni_res<<<512, 256, 0, stream>>>(AO, uni_W + d * CC * CHH,
                                       uni_b + d * CC, X, Y);
    k_inorm<<<256, 512, 0, stream>>>(Y, X, n1_g + d * CC, n1_b + d * CC);
    k_ffn<<<512, 256, 0, stream>>>(X, ffn_W1 + d * 128 * CC, ffn_b1 + d * 128,
                                   ffn_W2 + d * CC * 128, ffn_b2 + d * CC, Y);
    k_inorm<<<256, 512, 0, stream>>>(Y, X, n2_g + d * CC, n2_b + d * CC);
  }

  k_cls<<<64, 256, 0, stream>>>(X, cls_W, cls_b, (float*)d_out);
}

// Round 14
// 894.527 us; speedup vs baseline: 1.0176x; 1.0176x over previous
//
#include <hip/hip_runtime.h>
#include <math.h>

#define LL   2048
#define BB   8
#define CC   32
#define CHH  256
#define HH   8
#define DD   6

typedef _Float16 h8 __attribute__((ext_vector_type(8)));
typedef _Float16 h4 __attribute__((ext_vector_type(4)));
typedef float f4 __attribute__((ext_vector_type(4)));
typedef float f2v __attribute__((ext_vector_type(2)));

// ---------------------------------------------------------------- encoder
__global__ __launch_bounds__(256) void k_enc(const float* __restrict__ x,
    const float* __restrict__ W, const float* __restrict__ bias,
    float* __restrict__ X) {
  int idx = blockIdx.x * 256 + threadIdx.x;          // B*32*L = 524288
  int l = idx & (LL - 1);
  int c = (idx >> 11) & 31;
  int b = idx >> 16;
  float s = bias[c];
#pragma unroll
  for (int i = 0; i < 6; ++i)
    s = fmaf(W[c * 6 + i], x[((size_t)b * 6 + i) * LL + l], s);
  X[idx] = s;
}

// ------------- fused QKV: pointwise conv + depthwise conv3/conv15 + gate +
// cvt + layout (R6-verified form). grid (1024 = bh*16+lt, 3 z), 256 thr.
// LDS: Xt f32[32][144] @0 | o_tile 32x304B @18432 | Wt @28160 -> 32384.
__global__ __launch_bounds__(256) void k_qkv(const float* __restrict__ X,
    const float* __restrict__ pwq, const float* __restrict__ pwk,
    const float* __restrict__ pwv,
    const float* __restrict__ d3q, const float* __restrict__ d15q, const float* __restrict__ gq,
    const float* __restrict__ d3k, const float* __restrict__ d15k, const float* __restrict__ gk,
    const float* __restrict__ d3v, const float* __restrict__ d15v, const float* __restrict__ gv,
    _Float16* __restrict__ Qt, _Float16* __restrict__ Kt, _Float16* __restrict__ Vt) {
  __shared__ __align__(16) char lds[32384];
  int z  = blockIdx.y;
  int bx = blockIdx.x;
  int bh = bx >> 4, lt = bx & 15, l0 = lt * 128;
  int b = bh >> 3, h = bh & 7;
  int t = threadIdx.x;
  const float* pwp  = (z == 0) ? pwq  : (z == 1) ? pwk  : pwv;
  const float* w3p  = (z == 0) ? d3q  : (z == 1) ? d3k  : d3v;
  const float* w15p = (z == 0) ? d15q : (z == 1) ? d15k : d15v;
  const float* gp   = (z == 0) ? gq   : (z == 1) ? gk   : gv;

  float* Xt = (float*)lds;                     // [32][144]
  float* Wt = (float*)(lds + 28160);           // Wt[ci*33 + och]

  // ---- stage X tile [32 ci][144 l] (l = l0-8 .. l0+135, OOB zero)
  {
    int r = t >> 3, u = t & 7;
    const float* xr = X + ((size_t)b * CC + r) * LL;
    float* xd = Xt + r * 144;
#pragma unroll
    for (int s = u; s < 36; s += 8) {
      int ls = l0 - 8 + s * 4;
      f4 v;
      if (ls >= 0 && ls + 3 < LL) {
        v = *(const f4*)(xr + ls);
      } else {
#pragma unroll
        for (int e = 0; e < 4; ++e) {
          int l = ls + e;
          v[e] = (l >= 0 && l < LL) ? xr[l] : 0.f;
        }
      }
      *(f4*)(xd + s * 4) = v;
    }
  }
  // ---- stage W transposed: Wt[ci*33 + r] = pwp[(h*32+r)*32 + ci]
  {
    f4 wg = ((const f4*)(pwp + h * 1024))[t];
#pragma unroll
    for (int d2 = 0; d2 < 4; ++d2) {
      int e = t * 4 + d2;
      Wt[(e & 31) * 33 + (e >> 5)] = wg[d2];
    }
  }
  __syncthreads();

  // ---- phase 1: pointwise conv -> o_tile f16
  {
    int r = t & 31, seg = t >> 5;               // 18 l per (r,seg)
    float acc[18];
#pragma unroll
    for (int k = 0; k < 18; ++k) acc[k] = 0.f;
    for (int ci = 0; ci < 32; ++ci) {
      float w = Wt[ci * 33 + r];
      const f2v* X2 = (const f2v*)(Xt + ci * 144 + seg * 18);
#pragma unroll
      for (int m = 0; m < 9; ++m) {
        f2v xv = X2[m];
        acc[2 * m]     = fmaf(w, xv[0], acc[2 * m]);
        acc[2 * m + 1] = fmaf(w, xv[1], acc[2 * m + 1]);
      }
    }
    unsigned* orow = (unsigned*)(lds + 18432 + r * 304 + seg * 36);
#pragma unroll
    for (int m = 0; m < 9; ++m)
      orow[m] = __builtin_bit_cast(unsigned,
          __builtin_amdgcn_cvt_pkrtz(acc[2 * m], acc[2 * m + 1]));
  }
  __syncthreads();

  // ---- phase 2: depthwise conv3 + conv15 + softmax gate
  int c = t & 31, cg = t >> 5;
  float wv[32];
  {
    const h8* wp = (const h8*)(lds + 18432 + c * 304 + cg * 32);
#pragma unroll
    for (int q4 = 0; q4 < 4; ++q4) {
      h8 v = wp[q4];
#pragma unroll
      for (int e = 0; e < 8; ++e) wv[q4 * 8 + e] = (float)v[e];
    }
  }
  float r0 = gp[0], r1 = gp[1];
  float mx = fmaxf(r0, r1);
  float e0 = __expf(r0 - mx), e1 = __expf(r1 - mx);
  float gi = 1.f / (e0 + e1);
  float g0 = e0 * gi, g1 = e1 * gi;
  float sc = (z == 0) ? 0.2550765737f : 1.0f;   // C^-0.5 * log2(e) fold
  int ch = h * 32 + c;
  float w3r[3], w15r[15];
#pragma unroll
  for (int k = 0; k < 3; ++k)  w3r[k]  = w3p[ch * 3 + k];
#pragma unroll
  for (int k = 0; k < 15; ++k) w15r[k] = w15p[ch * 15 + k];

  h8 olo, ohi;
#pragma unroll
  for (int i = 0; i < 16; ++i) {
    float a = 0.f;
#pragma unroll
    for (int k = 0; k < 3; ++k) a = fmaf(w3r[k], wv[i + 7 + k], a);
    float s15 = 0.f;
#pragma unroll
    for (int k = 0; k < 15; ++k) s15 = fmaf(w15r[k], wv[i + 1 + k], s15);
    float val = (g0 * a + g1 * s15) * sc;
    if (i < 8) olo[i] = (_Float16)val; else ohi[i - 8] = (_Float16)val;
  }

  if (z == 2) {
    _Float16* dst = Vt + ((size_t)bh * 32 + c) * LL + l0 + cg * 16;
    *(h8*)dst = olo;
    *(h8*)(dst + 8) = ohi;
  } else {
    char* ot = lds;                             // reuse Xt region (dead)
#pragma unroll
    for (int i = 0; i < 16; ++i) {
      _Float16 v = (i < 8) ? olo[i] : ohi[i - 8];
      *(_Float16*)(ot + (cg * 16 + i) * 80 + c * 2) = v;
    }
    __syncthreads();
    _Float16* dst = ((z == 0) ? Qt : Kt) + ((size_t)bh * LL + l0) * 32;
    int l = t >> 1, hf = t & 1;
    uint4 a = *(uint4*)(ot + l * 80 + hf * 32);
    uint4 b2 = *(uint4*)(ot + l * 80 + hf * 32 + 16);
    *(uint4*)(dst + (size_t)l * 32 + hf * 16) = a;
    *(uint4*)(dst + (size_t)l * 32 + hf * 16 + 8) = b2;
  }
}

// ------------------------------------------------ MFMA flash attention (f16)
// R14: XCD-aware block swizzle (T1). Default linear order qb+16*bh makes
// the 16 qb-blocks sharing one bh's K/V consecutive -> round-robined across
// all 8 XCD L2s -> K/V duplicated ~8x (FETCH 69.7 MB vs ~12 MB unique).
// swz = (lin&7)*128 + lin>>3 (bijective, 1024=8x128) groups all 16 qb of a
// bh onto ONE XCD. Everything else = R4/R6 verified form: 8 waves,
// key-split, dbuf LDS, native exp2, permlane PV fragment, in-LDS merge.
__global__ __launch_bounds__(512, 2) void k_attn(
    const _Float16* __restrict__ Qt, const _Float16* __restrict__ Kt,
    const _Float16* __restrict__ Vt, _Float16* __restrict__ AO) {
  __shared__ __align__(16) char lds[38912];
  const int tid  = threadIdx.x;
  const int lane = tid & 63;
  const int w    = tid >> 6;                   // 0..7
  const int seg  = w >> 2;                     // 0..1: key segment
  const int wq   = w & 3;                      // q sub-block within 128
  const int g    = lane >> 4;
  const int ln   = lane & 15;
  const int h2c  = (wq >> 1) * 2;
  const int lin  = blockIdx.x + (blockIdx.y << 4);        // 0..1023
  const int swz  = ((lin & 7) << 7) | (lin >> 3);         // XCD-grouped
  const int qb   = swz & 15;                   // 0..15
  const int bh   = swz >> 4;                   // 0..63
  const _Float16* Qg = Qt + ((size_t)bh * LL + qb * 128) * 32;
  const _Float16* Kg = Kt + ((size_t)bh * LL + seg * 1024) * 32;
  const _Float16* Vg = Vt + (size_t)bh * 32 * LL + seg * 1024;

  h8 qf[2];
#pragma unroll
  for (int nt = 0; nt < 2; ++nt)
    qf[nt] = *(const h8*)(Qg + (size_t)(wq * 32 + nt * 16 + ln) * 32 + g * 8);

  h8 ones;
#pragma unroll
  for (int j = 0; j < 8; ++j) ones[j] = (_Float16)1.0f;

  char* kb = lds + seg * 5120;                 // + p*10240
  char* vb = lds + 20480 + seg * 4608;         // + p*9216

  uint4 stg0, stg1;
  if ((wq & 1) == 0) {
    const uint4* gk = (const uint4*)Kg;
    stg0 = gk[h2c * 64 + lane];
    stg1 = gk[(h2c + 1) * 64 + lane];
    *(uint4*)(kb + (h2c * 16 + (lane >> 2)) * 80 + (lane & 3) * 16) = stg0;
    *(uint4*)(kb + ((h2c + 1) * 16 + (lane >> 2)) * 80 + (lane & 3) * 16) = stg1;
  } else {
    int c0 = h2c * 8 + (lane >> 3);
    stg0 = *(const uint4*)(Vg + (size_t)c0 * LL + (lane & 7) * 8);
    stg1 = *(const uint4*)(Vg + (size_t)(c0 + 8) * LL + (lane & 7) * 8);
    *(uint4*)(vb + c0 * 144 + (lane & 7) * 16) = stg0;
    *(uint4*)(vb + (c0 + 8) * 144 + (lane & 7) * 16) = stg1;
  }
  __syncthreads();

  f4 o[2][2];
#pragma unroll
  for (int ct = 0; ct < 2; ++ct)
#pragma unroll
    for (int nt = 0; nt < 2; ++nt) o[ct][nt] = (f4){0.f, 0.f, 0.f, 0.f};
  f4 sacc[2];
#pragma unroll
  for (int nt = 0; nt < 2; ++nt) sacc[nt] = (f4){0.f, 0.f, 0.f, 0.f};

  for (int it = 0; it < 16; ++it) {
    int pp = it & 1;
    char* kbc = kb + pp * 10240;
    char* vbc = vb + pp * 9216;
    if (it < 15) {
      int k0n = (it + 1) * 64;
      if ((wq & 1) == 0) {
        const uint4* gk = (const uint4*)(Kg + (size_t)k0n * 32);
        stg0 = gk[h2c * 64 + lane];
        stg1 = gk[(h2c + 1) * 64 + lane];
      } else {
        int c0 = h2c * 8 + (lane >> 3);
        stg0 = *(const uint4*)(Vg + (size_t)c0 * LL + k0n + (lane & 7) * 8);
        stg1 = *(const uint4*)(Vg + (size_t)(c0 + 8) * LL + k0n + (lane & 7) * 8);
      }
    }
#pragma unroll
    for (int chunk = 0; chunk < 2; ++chunk) {
      unsigned pa[2][2], pb[2][2];
#pragma unroll
      for (int mt2 = 0; mt2 < 2; ++mt2) {
        h8 kf = *(const h8*)(kbc + ((chunk * 2 + mt2) * 16 + ln) * 80 + g * 16);
#pragma unroll
        for (int nt = 0; nt < 2; ++nt) {
          f4 z = {0.f, 0.f, 0.f, 0.f};
          f4 s = __builtin_amdgcn_mfma_f32_16x16x32_f16(kf, qf[nt], z, 0, 0, 0);
          float p0 = __builtin_amdgcn_exp2f(s[0]);
          float p1 = __builtin_amdgcn_exp2f(s[1]);
          float p2 = __builtin_amdgcn_exp2f(s[2]);
          float p3 = __builtin_amdgcn_exp2f(s[3]);
          unsigned lo = __builtin_bit_cast(unsigned,
              __builtin_amdgcn_cvt_pkrtz(p0, p1));
          unsigned hi = __builtin_bit_cast(unsigned,
              __builtin_amdgcn_cvt_pkrtz(p2, p3));
          if (mt2 == 0) { pa[nt][0] = lo; pa[nt][1] = hi; }
          else          { pb[nt][0] = lo; pb[nt][1] = hi; }
        }
      }
      h8 vf[2];
#pragma unroll
      for (int ct = 0; ct < 2; ++ct)
        vf[ct] = *(const h8*)(vbc + (ct * 16 + ln) * 144 + chunk * 64 + g * 16);
#pragma unroll
      for (int nt = 0; nt < 2; ++nt) {
        unsigned w0 = pa[nt][0], w1 = pa[nt][1];
        unsigned w2 = pb[nt][0], w3 = pb[nt][1];
        asm("v_permlane32_swap_b32 %0, %1" : "+v"(w0), "+v"(w2));
        asm("v_permlane16_swap_b32 %0, %1" : "+v"(w0), "+v"(w2));
        asm("v_permlane32_swap_b32 %0, %1" : "+v"(w1), "+v"(w3));
        asm("v_permlane16_swap_b32 %0, %1" : "+v"(w1), "+v"(w3));
        uint4 pw4; pw4.x = w0; pw4.y = w1; pw4.z = w2; pw4.w = w3;
        h8 pf = __builtin_bit_cast(h8, pw4);
        sacc[nt] = __builtin_amdgcn_mfma_f32_16x16x32_f16(ones, pf, sacc[nt], 0, 0, 0);
        o[0][nt] = __builtin_amdgcn_mfma_f32_16x16x32_f16(vf[0], pf, o[0][nt], 0, 0, 0);
        o[1][nt] = __builtin_amdgcn_mfma_f32_16x16x32_f16(vf[1], pf, o[1][nt], 0, 0, 0);
      }
    }
    if (it < 15) {
      char* kbn = kb + (pp ^ 1) * 10240;
      char* vbn = vb + (pp ^ 1) * 9216;
      if ((wq & 1) == 0) {
        *(uint4*)(kbn + (h2c * 16 + (lane >> 2)) * 80 + (lane & 3) * 16) = stg0;
        *(uint4*)(kbn + ((h2c + 1) * 16 + (lane >> 2)) * 80 + (lane & 3) * 16) = stg1;
      } else {
        int c0 = h2c * 8 + (lane >> 3);
        *(uint4*)(vbn + c0 * 144 + (lane & 7) * 16) = stg0;
        *(uint4*)(vbn + (c0 + 8) * 144 + (lane & 7) * 16) = stg1;
      }
    }
    __syncthreads();
  }

  if (seg == 1) {
    char* eo = lds + wq * 9216 + lane * 144;
#pragma unroll
    for (int nt = 0; nt < 2; ++nt)
#pragma unroll
      for (int ct = 0; ct < 2; ++ct)
        *(f4*)(eo + (nt * 2 + ct) * 16) = o[ct][nt];
    f4 sv;
    sv[0] = sacc[0][0]; sv[1] = sacc[1][0];
    sv[2] = 0.f; sv[3] = 0.f;
    *(f4*)(eo + 64) = sv;
  }
  __syncthreads();
  if (seg == 0) {
    const char* po = lds + wq * 9216 + lane * 144;
    f4 s1v = *(const f4*)(po + 64);
    _Float16* out = AO + (size_t)bh * (32 * LL);
#pragma unroll
    for (int nt = 0; nt < 2; ++nt) {
      float inv = 1.f / (sacc[nt][0] + s1v[nt]);
      int qg = qb * 128 + wq * 32 + nt * 16 + ln;
#pragma unroll
      for (int ct = 0; ct < 2; ++ct) {
        f4 o1 = *(const f4*)(po + (nt * 2 + ct) * 16);
#pragma unroll
        for (int r = 0; r < 4; ++r)
          out[(size_t)(ct * 16 + g * 4 + r) * LL + qg] =
              (_Float16)((o[ct][nt][r] + o1[r]) * inv);
      }
    }
  }
}

// -------- uni GEMM [32,256] f16-in + bias + residual (R10-verified form).
// grid 512 (8b x 32lt x 2half), 64 l per block, cc-split 4.
__global__ __launch_bounds__(256) void k_uni_res(const _Float16* __restrict__ AO,
    const float* __restrict__ W, const float* __restrict__ bias,
    const float* __restrict__ Xin, float* __restrict__ Y) {
  __shared__ float ps[3][64 * 17];
  int t    = threadIdx.x;
  int li   = t & 63;
  int cg   = t >> 6;                            // 0..3: cc quarter
  int bx   = blockIdx.x;                        // 512 blocks
  int lt   = bx & 31;
  int half = (bx >> 5) & 1;
  int b    = bx >> 6;
  int l    = lt * 64 + li;
  const _Float16* ap = AO + (size_t)b * CHH * LL + cg * 64 * (size_t)LL + l;
  float acc[16];
#pragma unroll
  for (int j = 0; j < 16; ++j) acc[j] = 0.f;
  for (int cc = 0; cc < 64; cc += 4) {
    float a0 = (float)ap[(size_t)(cc + 0) * LL];
    float a1 = (float)ap[(size_t)(cc + 1) * LL];
    float a2 = (float)ap[(size_t)(cc + 2) * LL];
    float a3 = (float)ap[(size_t)(cc + 3) * LL];
#pragma unroll
    for (int j = 0; j < 16; ++j) {
      const float* wr = W + (half * 16 + j) * CHH + cg * 64 + cc;
      acc[j] = fmaf(wr[0], a0, acc[j]);
      acc[j] = fmaf(wr[1], a1, acc[j]);
      acc[j] = fmaf(wr[2], a2, acc[j]);
      acc[j] = fmaf(wr[3], a3, acc[j]);
    }
  }
  if (cg) {
#pragma unroll
    for (int j = 0; j < 16; ++j) ps[cg - 1][li * 17 + j] = acc[j];
  }
  __syncthreads();
  if (!cg) {
#pragma unroll
    for (int j = 0; j < 16; ++j) {
      int c = half * 16 + j;
      size_t o = ((size_t)b * CC + c) * LL + l;
      Y[o] = acc[j] + ps[0][li * 17 + j] + ps[1][li * 17 + j] +
             ps[2][li * 17 + j] + bias[c] + Xin[o];
    }
  }
}

// ---------------------------------------------------------- instance norm
// (R10-verified form: 512 threads, 4 elems/thread.)
__global__ __launch_bounds__(512) void k_inorm(const float* __restrict__ Y,
    float* __restrict__ X, const float* __restrict__ g,
    const float* __restrict__ bt) {
  __shared__ float red[16];
  int row = blockIdx.x;
  int c = row & 31;
  const float* y = Y + (size_t)row * LL;
  float v[4];
  float s = 0.f, ss = 0.f;
#pragma unroll
  for (int i = 0; i < 4; ++i) {
    v[i] = y[threadIdx.x + 512 * i];
    s += v[i];
    ss = fmaf(v[i], v[i], ss);
  }
#pragma unroll
  for (int off = 32; off; off >>= 1) {
    s  += __shfl_down(s, off);
    ss += __shfl_down(ss, off);
  }
  int wid = threadIdx.x >> 6;
  if ((threadIdx.x & 63) == 0) { red[wid * 2] = s; red[wid * 2 + 1] = ss; }
  __syncthreads();
  if (threadIdx.x == 0) {
    float rs0 = 0.f, rs1 = 0.f;
#pragma unroll
    for (int i = 0; i < 8; ++i) { rs0 += red[i * 2]; rs1 += red[i * 2 + 1]; }
    red[0] = rs0; red[1] = rs1;
  }
  __syncthreads();
  float mean = red[0] * (1.f / LL);
  float var  = red[1] * (1.f / LL) - mean * mean;
  float rs = rsqrtf(var + 1e-5f) * g[c];
  float bb = bt[c];
#pragma unroll
  for (int i = 0; i < 4; ++i)
    X[(size_t)row * LL + threadIdx.x + 512 * i] = (v[i] - mean) * rs + bb;
}

// -------- fused FFN v5 (R10-verified): LDS-staged weights, phase-split.
// LDS: wlds 33.3KB + ps 29.6KB = 62.8KB -> 2 blocks/CU.
__global__ __launch_bounds__(256) void k_ffn(const float* __restrict__ X,
    const float* __restrict__ W1, const float* __restrict__ b1,
    const float* __restrict__ W2, const float* __restrict__ b2,
    float* __restrict__ Y) {
  __shared__ __align__(16) float wlds[8320];    // W1 @0, W2 @4096, b1 @8192
  __shared__ float ps[7][32 * 33];
  int bx = blockIdx.x;                          // 8b * 64lt
  int b = bx >> 6;
  int l0 = (bx & 63) * 32;
  int t = threadIdx.x;
  int li = t & 31;
  int og = t >> 5;                              // 0..7
  int l = l0 + li;
  // ---- stage weights to LDS (coalesced f4)
#pragma unroll
  for (int i = 0; i < 4; ++i)
    ((f4*)wlds)[t + i * 256] = ((const f4*)W1)[t + i * 256];
#pragma unroll
  for (int i = 0; i < 4; ++i)
    ((f4*)(wlds + 4096))[t + i * 256] = ((const f4*)W2)[t + i * 256];
  if (t < 32) ((f4*)(wlds + 8192))[t] = ((const f4*)b1)[t];

  const float* Xp = X + (size_t)b * CC * LL + l;
  float xv[32];
#pragma unroll
  for (int c = 0; c < 32; ++c) xv[c] = Xp[(size_t)c * LL];
  __syncthreads();

  // ---- phase A: 16 hidden units, 4-wide partial chains from LDS
  float hs[16];
#pragma unroll
  for (int op = 0; op < 16; ++op) {
    int o = og * 16 + op;
    const f4* wr = (const f4*)(wlds + o * 32);
    f4 p = {wlds[8192 + o], 0.f, 0.f, 0.f};
#pragma unroll
    for (int c4 = 0; c4 < 8; ++c4) {
      f4 a = wr[c4];
      p[0] = fmaf(a[0], xv[c4 * 4 + 0], p[0]);
      p[1] = fmaf(a[1], xv[c4 * 4 + 1], p[1]);
      p[2] = fmaf(a[2], xv[c4 * 4 + 2], p[2]);
      p[3] = fmaf(a[3], xv[c4 * 4 + 3], p[3]);
    }
    hs[op] = fmaxf((p[0] + p[1]) + (p[2] + p[3]), 0.f);
  }

  // ---- phase B: 32 outputs, f4 W2 reads from LDS
  float acc[32];
#pragma unroll
  for (int c = 0; c < 32; ++c) {
    const f4* w2r = (const f4*)(wlds + 4096 + c * 128 + og * 16);
    f4 s = {0.f, 0.f, 0.f, 0.f};
#pragma unroll
    for (int o4 = 0; o4 < 4; ++o4) {
      f4 w = w2r[o4];
      s[0] = fmaf(w[0], hs[o4 * 4 + 0], s[0]);
      s[1] = fmaf(w[1], hs[o4 * 4 + 1], s[1]);
      s[2] = fmaf(w[2], hs[o4 * 4 + 2], s[2]);
      s[3] = fmaf(w[3], hs[o4 * 4 + 3], s[3]);
    }
    acc[c] = (s[0] + s[1]) + (s[2] + s[3]);
  }

  if (og) {
#pragma unroll
    for (int c = 0; c < 32; ++c) ps[og - 1][li * 33 + c] = acc[c];
  }
  __syncthreads();
  if (!og) {
    float* Yp = Y + (size_t)b * CC * LL + l;
#pragma unroll
    for (int c = 0; c < 32; ++c) {
      float r = acc[c] + b2[c] + xv[c];
#pragma unroll
      for (int q = 0; q < 7; ++q) r += ps[q][li * 33 + c];
      Yp[(size_t)c * LL] = r;
    }
  }
}

// ------------------------------------------------------------- classifier
__global__ __launch_bounds__(256) void k_cls(const float* __restrict__ X,
    const float* __restrict__ W, const float* __restrict__ bias,
    float* __restrict__ out) {
  int idx = blockIdx.x * 256 + threadIdx.x;
  int l = idx & (LL - 1);
  int b = idx >> 11;
  float s = bias[0];
#pragma unroll
  for (int c = 0; c < CC; ++c)
    s = fmaf(W[c], X[((size_t)b * CC + c) * LL + l], s);
  out[idx] = 1.f / (1.f + __expf(-s));
}

// ------------------------------------------------------------------ launch
extern "C" void kernel_launch(void* const* d_in, const int* in_sizes, int n_in,
                              void* d_out, int out_size, void* d_ws,
                              size_t ws_size, hipStream_t stream) {
  const float* x      = (const float*)d_in[0];
  const float* enc_W  = (const float*)d_in[1];
  const float* enc_b  = (const float*)d_in[2];
  const float* pw_q   = (const float*)d_in[3];
  const float* dw3_q  = (const float*)d_in[4];
  const float* dw15_q = (const float*)d_in[5];
  const float* gate_q = (const float*)d_in[6];
  const float* pw_k   = (const float*)d_in[7];
  const float* dw3_k  = (const float*)d_in[8];
  const float* dw15_k = (const float*)d_in[9];
  const float* gate_k = (const float*)d_in[10];
  const float* pw_v   = (const float*)d_in[11];
  const float* dw3_v  = (const float*)d_in[12];
  const float* dw15_v = (const float*)d_in[13];
  const float* gate_v = (const float*)d_in[14];
  const float* uni_W  = (const float*)d_in[15];
  const float* uni_b  = (const float*)d_in[16];
  const float* n1_g   = (const float*)d_in[17];
  const float* n1_b   = (const float*)d_in[18];
  const float* n2_g   = (const float*)d_in[19];
  const float* n2_b   = (const float*)d_in[20];
  const float* ffn_W1 = (const float*)d_in[21];
  const float* ffn_b1 = (const float*)d_in[22];
  const float* ffn_W2 = (const float*)d_in[23];
  const float* ffn_b2 = (const float*)d_in[24];
  const float* cls_W  = (const float*)d_in[25];
  const float* cls_b  = (const float*)d_in[26];

  float* ws = (float*)d_ws;
  float* X   = ws;                             // [B,32,L] fp32
  float* Y   = ws + 524288;                    // [B,32,L] fp32
  _Float16* AO = (_Float16*)(ws + 1048576);    // [B,256,L] f16 attn out
  _Float16* Qt = (_Float16*)(ws + 9437184);    // [64bh][L][32c] f16
  _Float16* Kt = (_Float16*)(ws + 11534336);   // [64bh][L][32c] f16
  _Float16* Vt = (_Float16*)(ws + 13631488);   // [64bh][32c][L] f16

  k_enc<<<2048, 256, 0, stream>>>(x, enc_W, enc_b, X);

  for (int d = 0; d < DD; ++d) {
    k_qkv<<<dim3(1024, 3), 256, 0, stream>>>(X,
        pw_q + d * CHH * CC, pw_k + d * CHH * CC, pw_v + d * CHH * CC,
        dw3_q + d * CHH * 3, dw15_q + d * CHH * 15, gate_q + d * 2,
        dw3_k + d * CHH * 3, dw15_k + d * CHH * 15, gate_k + d * 2,
        dw3_v + d * CHH * 3, dw15_v + d * CHH * 15, gate_v + d * 2,
        Qt, Kt, Vt);
    k_attn<<<dim3(16, 64), 512, 0, stream>>>(Qt, Kt, Vt, AO);
    k_uni_res<<<512, 256, 0, stream>>>(AO, uni_W + d * CC * CHH,
                                       uni_b + d * CC, X, Y);
    k_inorm<<<256, 512, 0, stream>>>(Y, X, n1_g + d * CC, n1_b + d * CC);
    k_ffn<<<512, 256, 0, stream>>>(X, ffn_W1 + d * 128 * CC, ffn_b1 + d * 128,
                                   ffn_W2 + d * CC * 128, ffn_b2 + d * CC, Y);
    k_inorm<<<256, 512, 0, stream>>>(Y, X, n2_g + d * CC, n2_b + d * CC);
  }

  k_cls<<<64, 256, 0, stream>>>(X, cls_W, cls_b, (float*)d_out);
}

// Round 15
// 882.746 us; speedup vs baseline: 1.0312x; 1.0133x over previous
//
#include <hip/hip_runtime.h>
#include <math.h>

#define LL   2048
#define BB   8
#define CC   32
#define CHH  256
#define HH   8
#define DD   6

typedef _Float16 h8 __attribute__((ext_vector_type(8)));
typedef _Float16 h4 __attribute__((ext_vector_type(4)));
typedef float f4 __attribute__((ext_vector_type(4)));
typedef float f2v __attribute__((ext_vector_type(2)));

// ---------------------------------------------------------------- encoder
__global__ __launch_bounds__(256) void k_enc(const float* __restrict__ x,
    const float* __restrict__ W, const float* __restrict__ bias,
    float* __restrict__ X) {
  int idx = blockIdx.x * 256 + threadIdx.x;          // B*32*L = 524288
  int l = idx & (LL - 1);
  int c = (idx >> 11) & 31;
  int b = idx >> 16;
  float s = bias[c];
#pragma unroll
  for (int i = 0; i < 6; ++i)
    s = fmaf(W[c * 6 + i], x[((size_t)b * 6 + i) * LL + l], s);
  X[idx] = s;
}

// ------------- fused QKV: pointwise conv + depthwise conv3/conv15 + gate +
// cvt + layout (R6-verified form). grid (1024 = bh*16+lt, 3 z), 256 thr.
// LDS: Xt f32[32][144] @0 | o_tile 32x304B @18432 | Wt @28160 -> 32384.
__global__ __launch_bounds__(256) void k_qkv(const float* __restrict__ X,
    const float* __restrict__ pwq, const float* __restrict__ pwk,
    const float* __restrict__ pwv,
    const float* __restrict__ d3q, const float* __restrict__ d15q, const float* __restrict__ gq,
    const float* __restrict__ d3k, const float* __restrict__ d15k, const float* __restrict__ gk,
    const float* __restrict__ d3v, const float* __restrict__ d15v, const float* __restrict__ gv,
    _Float16* __restrict__ Qt, _Float16* __restrict__ Kt, _Float16* __restrict__ Vt) {
  __shared__ __align__(16) char lds[32384];
  int z  = blockIdx.y;
  int bx = blockIdx.x;
  int bh = bx >> 4, lt = bx & 15, l0 = lt * 128;
  int b = bh >> 3, h = bh & 7;
  int t = threadIdx.x;
  const float* pwp  = (z == 0) ? pwq  : (z == 1) ? pwk  : pwv;
  const float* w3p  = (z == 0) ? d3q  : (z == 1) ? d3k  : d3v;
  const float* w15p = (z == 0) ? d15q : (z == 1) ? d15k : d15v;
  const float* gp   = (z == 0) ? gq   : (z == 1) ? gk   : gv;

  float* Xt = (float*)lds;                     // [32][144]
  float* Wt = (float*)(lds + 28160);           // Wt[ci*33 + och]

  // ---- stage X tile [32 ci][144 l] (l = l0-8 .. l0+135, OOB zero)
  {
    int r = t >> 3, u = t & 7;
    const float* xr = X + ((size_t)b * CC + r) * LL;
    float* xd = Xt + r * 144;
#pragma unroll
    for (int s = u; s < 36; s += 8) {
      int ls = l0 - 8 + s * 4;
      f4 v;
      if (ls >= 0 && ls + 3 < LL) {
        v = *(const f4*)(xr + ls);
      } else {
#pragma unroll
        for (int e = 0; e < 4; ++e) {
          int l = ls + e;
          v[e] = (l >= 0 && l < LL) ? xr[l] : 0.f;
        }
      }
      *(f4*)(xd + s * 4) = v;
    }
  }
  // ---- stage W transposed: Wt[ci*33 + r] = pwp[(h*32+r)*32 + ci]
  {
    f4 wg = ((const f4*)(pwp + h * 1024))[t];
#pragma unroll
    for (int d2 = 0; d2 < 4; ++d2) {
      int e = t * 4 + d2;
      Wt[(e & 31) * 33 + (e >> 5)] = wg[d2];
    }
  }
  __syncthreads();

  // ---- phase 1: pointwise conv -> o_tile f16
  {
    int r = t & 31, seg = t >> 5;               // 18 l per (r,seg)
    float acc[18];
#pragma unroll
    for (int k = 0; k < 18; ++k) acc[k] = 0.f;
    for (int ci = 0; ci < 32; ++ci) {
      float w = Wt[ci * 33 + r];
      const f2v* X2 = (const f2v*)(Xt + ci * 144 + seg * 18);
#pragma unroll
      for (int m = 0; m < 9; ++m) {
        f2v xv = X2[m];
        acc[2 * m]     = fmaf(w, xv[0], acc[2 * m]);
        acc[2 * m + 1] = fmaf(w, xv[1], acc[2 * m + 1]);
      }
    }
    unsigned* orow = (unsigned*)(lds + 18432 + r * 304 + seg * 36);
#pragma unroll
    for (int m = 0; m < 9; ++m)
      orow[m] = __builtin_bit_cast(unsigned,
          __builtin_amdgcn_cvt_pkrtz(acc[2 * m], acc[2 * m + 1]));
  }
  __syncthreads();

  // ---- phase 2: depthwise conv3 + conv15 + softmax gate
  int c = t & 31, cg = t >> 5;
  float wv[32];
  {
    const h8* wp = (const h8*)(lds + 18432 + c * 304 + cg * 32);
#pragma unroll
    for (int q4 = 0; q4 < 4; ++q4) {
      h8 v = wp[q4];
#pragma unroll
      for (int e = 0; e < 8; ++e) wv[q4 * 8 + e] = (float)v[e];
    }
  }
  float r0 = gp[0], r1 = gp[1];
  float mx = fmaxf(r0, r1);
  float e0 = __expf(r0 - mx), e1 = __expf(r1 - mx);
  float gi = 1.f / (e0 + e1);
  float g0 = e0 * gi, g1 = e1 * gi;
  float sc = (z == 0) ? 0.2550765737f : 1.0f;   // C^-0.5 * log2(e) fold
  int ch = h * 32 + c;
  float w3r[3], w15r[15];
#pragma unroll
  for (int k = 0; k < 3; ++k)  w3r[k]  = w3p[ch * 3 + k];
#pragma unroll
  for (int k = 0; k < 15; ++k) w15r[k] = w15p[ch * 15 + k];

  h8 olo, ohi;
#pragma unroll
  for (int i = 0; i < 16; ++i) {
    float a = 0.f;
#pragma unroll
    for (int k = 0; k < 3; ++k) a = fmaf(w3r[k], wv[i + 7 + k], a);
    float s15 = 0.f;
#pragma unroll
    for (int k = 0; k < 15; ++k) s15 = fmaf(w15r[k], wv[i + 1 + k], s15);
    float val = (g0 * a + g1 * s15) * sc;
    if (i < 8) olo[i] = (_Float16)val; else ohi[i - 8] = (_Float16)val;
  }

  if (z == 2) {
    _Float16* dst = Vt + ((size_t)bh * 32 + c) * LL + l0 + cg * 16;
    *(h8*)dst = olo;
    *(h8*)(dst + 8) = ohi;
  } else {
    char* ot = lds;                             // reuse Xt region (dead)
#pragma unroll
    for (int i = 0; i < 16; ++i) {
      _Float16 v = (i < 8) ? olo[i] : ohi[i - 8];
      *(_Float16*)(ot + (cg * 16 + i) * 80 + c * 2) = v;
    }
    __syncthreads();
    _Float16* dst = ((z == 0) ? Qt : Kt) + ((size_t)bh * LL + l0) * 32;
    int l = t >> 1, hf = t & 1;
    uint4 a = *(uint4*)(ot + l * 80 + hf * 32);
    uint4 b2 = *(uint4*)(ot + l * 80 + hf * 32 + 16);
    *(uint4*)(dst + (size_t)l * 32 + hf * 16) = a;
    *(uint4*)(dst + (size_t)l * 32 + hf * 16 + 8) = b2;
  }
}

// ------------------------------------------------ MFMA flash attention (f16)
// R14-verified: XCD-aware block swizzle (FETCH 69.7->12.3 MB confirmed) +
// R4/R6 core: 8 waves, key-split, dbuf LDS, native exp2, permlane PV
// fragment, in-LDS merge.
__global__ __launch_bounds__(512, 2) void k_attn(
    const _Float16* __restrict__ Qt, const _Float16* __restrict__ Kt,
    const _Float16* __restrict__ Vt, _Float16* __restrict__ AO) {
  __shared__ __align__(16) char lds[38912];
  const int tid  = threadIdx.x;
  const int lane = tid & 63;
  const int w    = tid >> 6;                   // 0..7
  const int seg  = w >> 2;                     // 0..1: key segment
  const int wq   = w & 3;                      // q sub-block within 128
  const int g    = lane >> 4;
  const int ln   = lane & 15;
  const int h2c  = (wq >> 1) * 2;
  const int lin  = blockIdx.x + (blockIdx.y << 4);        // 0..1023
  const int swz  = ((lin & 7) << 7) | (lin >> 3);         // XCD-grouped
  const int qb   = swz & 15;                   // 0..15
  const int bh   = swz >> 4;                   // 0..63
  const _Float16* Qg = Qt + ((size_t)bh * LL + qb * 128) * 32;
  const _Float16* Kg = Kt + ((size_t)bh * LL + seg * 1024) * 32;
  const _Float16* Vg = Vt + (size_t)bh * 32 * LL + seg * 1024;

  h8 qf[2];
#pragma unroll
  for (int nt = 0; nt < 2; ++nt)
    qf[nt] = *(const h8*)(Qg + (size_t)(wq * 32 + nt * 16 + ln) * 32 + g * 8);

  h8 ones;
#pragma unroll
  for (int j = 0; j < 8; ++j) ones[j] = (_Float16)1.0f;

  char* kb = lds + seg * 5120;                 // + p*10240
  char* vb = lds + 20480 + seg * 4608;         // + p*9216

  uint4 stg0, stg1;
  if ((wq & 1) == 0) {
    const uint4* gk = (const uint4*)Kg;
    stg0 = gk[h2c * 64 + lane];
    stg1 = gk[(h2c + 1) * 64 + lane];
    *(uint4*)(kb + (h2c * 16 + (lane >> 2)) * 80 + (lane & 3) * 16) = stg0;
    *(uint4*)(kb + ((h2c + 1) * 16 + (lane >> 2)) * 80 + (lane & 3) * 16) = stg1;
  } else {
    int c0 = h2c * 8 + (lane >> 3);
    stg0 = *(const uint4*)(Vg + (size_t)c0 * LL + (lane & 7) * 8);
    stg1 = *(const uint4*)(Vg + (size_t)(c0 + 8) * LL + (lane & 7) * 8);
    *(uint4*)(vb + c0 * 144 + (lane & 7) * 16) = stg0;
    *(uint4*)(vb + (c0 + 8) * 144 + (lane & 7) * 16) = stg1;
  }
  __syncthreads();

  f4 o[2][2];
#pragma unroll
  for (int ct = 0; ct < 2; ++ct)
#pragma unroll
    for (int nt = 0; nt < 2; ++nt) o[ct][nt] = (f4){0.f, 0.f, 0.f, 0.f};
  f4 sacc[2];
#pragma unroll
  for (int nt = 0; nt < 2; ++nt) sacc[nt] = (f4){0.f, 0.f, 0.f, 0.f};

  for (int it = 0; it < 16; ++it) {
    int pp = it & 1;
    char* kbc = kb + pp * 10240;
    char* vbc = vb + pp * 9216;
    if (it < 15) {
      int k0n = (it + 1) * 64;
      if ((wq & 1) == 0) {
        const uint4* gk = (const uint4*)(Kg + (size_t)k0n * 32);
        stg0 = gk[h2c * 64 + lane];
        stg1 = gk[(h2c + 1) * 64 + lane];
      } else {
        int c0 = h2c * 8 + (lane >> 3);
        stg0 = *(const uint4*)(Vg + (size_t)c0 * LL + k0n + (lane & 7) * 8);
        stg1 = *(const uint4*)(Vg + (size_t)(c0 + 8) * LL + k0n + (lane & 7) * 8);
      }
    }
#pragma unroll
    for (int chunk = 0; chunk < 2; ++chunk) {
      unsigned pa[2][2], pb[2][2];
#pragma unroll
      for (int mt2 = 0; mt2 < 2; ++mt2) {
        h8 kf = *(const h8*)(kbc + ((chunk * 2 + mt2) * 16 + ln) * 80 + g * 16);
#pragma unroll
        for (int nt = 0; nt < 2; ++nt) {
          f4 z = {0.f, 0.f, 0.f, 0.f};
          f4 s = __builtin_amdgcn_mfma_f32_16x16x32_f16(kf, qf[nt], z, 0, 0, 0);
          float p0 = __builtin_amdgcn_exp2f(s[0]);
          float p1 = __builtin_amdgcn_exp2f(s[1]);
          float p2 = __builtin_amdgcn_exp2f(s[2]);
          float p3 = __builtin_amdgcn_exp2f(s[3]);
          unsigned lo = __builtin_bit_cast(unsigned,
              __builtin_amdgcn_cvt_pkrtz(p0, p1));
          unsigned hi = __builtin_bit_cast(unsigned,
              __builtin_amdgcn_cvt_pkrtz(p2, p3));
          if (mt2 == 0) { pa[nt][0] = lo; pa[nt][1] = hi; }
          else          { pb[nt][0] = lo; pb[nt][1] = hi; }
        }
      }
      h8 vf[2];
#pragma unroll
      for (int ct = 0; ct < 2; ++ct)
        vf[ct] = *(const h8*)(vbc + (ct * 16 + ln) * 144 + chunk * 64 + g * 16);
#pragma unroll
      for (int nt = 0; nt < 2; ++nt) {
        unsigned w0 = pa[nt][0], w1 = pa[nt][1];
        unsigned w2 = pb[nt][0], w3 = pb[nt][1];
        asm("v_permlane32_swap_b32 %0, %1" : "+v"(w0), "+v"(w2));
        asm("v_permlane16_swap_b32 %0, %1" : "+v"(w0), "+v"(w2));
        asm("v_permlane32_swap_b32 %0, %1" : "+v"(w1), "+v"(w3));
        asm("v_permlane16_swap_b32 %0, %1" : "+v"(w1), "+v"(w3));
        uint4 pw4; pw4.x = w0; pw4.y = w1; pw4.z = w2; pw4.w = w3;
        h8 pf = __builtin_bit_cast(h8, pw4);
        sacc[nt] = __builtin_amdgcn_mfma_f32_16x16x32_f16(ones, pf, sacc[nt], 0, 0, 0);
        o[0][nt] = __builtin_amdgcn_mfma_f32_16x16x32_f16(vf[0], pf, o[0][nt], 0, 0, 0);
        o[1][nt] = __builtin_amdgcn_mfma_f32_16x16x32_f16(vf[1], pf, o[1][nt], 0, 0, 0);
      }
    }
    if (it < 15) {
      char* kbn = kb + (pp ^ 1) * 10240;
      char* vbn = vb + (pp ^ 1) * 9216;
      if ((wq & 1) == 0) {
        *(uint4*)(kbn + (h2c * 16 + (lane >> 2)) * 80 + (lane & 3) * 16) = stg0;
        *(uint4*)(kbn + ((h2c + 1) * 16 + (lane >> 2)) * 80 + (lane & 3) * 16) = stg1;
      } else {
        int c0 = h2c * 8 + (lane >> 3);
        *(uint4*)(vbn + c0 * 144 + (lane & 7) * 16) = stg0;
        *(uint4*)(vbn + (c0 + 8) * 144 + (lane & 7) * 16) = stg1;
      }
    }
    __syncthreads();
  }

  if (seg == 1) {
    char* eo = lds + wq * 9216 + lane * 144;
#pragma unroll
    for (int nt = 0; nt < 2; ++nt)
#pragma unroll
      for (int ct = 0; ct < 2; ++ct)
        *(f4*)(eo + (nt * 2 + ct) * 16) = o[ct][nt];
    f4 sv;
    sv[0] = sacc[0][0]; sv[1] = sacc[1][0];
    sv[2] = 0.f; sv[3] = 0.f;
    *(f4*)(eo + 64) = sv;
  }
  __syncthreads();
  if (seg == 0) {
    const char* po = lds + wq * 9216 + lane * 144;
    f4 s1v = *(const f4*)(po + 64);
    _Float16* out = AO + (size_t)bh * (32 * LL);
#pragma unroll
    for (int nt = 0; nt < 2; ++nt) {
      float inv = 1.f / (sacc[nt][0] + s1v[nt]);
      int qg = qb * 128 + wq * 32 + nt * 16 + ln;
#pragma unroll
      for (int ct = 0; ct < 2; ++ct) {
        f4 o1 = *(const f4*)(po + (nt * 2 + ct) * 16);
#pragma unroll
        for (int r = 0; r < 4; ++r)
          out[(size_t)(ct * 16 + g * 4 + r) * LL + qg] =
              (_Float16)((o[ct][nt][r] + o1[r]) * inv);
      }
    }
  }
}

// -------- uni GEMM [32,256] f16-in + bias + residual, v5.
// R15: double TLP for the latency-bound AO loads — R14 ran 512 blocks =
// 2 blocks/CU = 8 waves/CU with 64 L2-latency loads/thread (VALU floor
// ~1.7us vs ~25us measured = >90% stall). Now 32-l tiles, cc-split 8 ->
// grid 1024 = 4 blocks/CU, 16 waves/CU. Same loads/FMAs per element; W
// s_load pattern unchanged (R11 lesson). LDS ps 7x32x17 = 15.2 KB.
__global__ __launch_bounds__(256) void k_uni_res(const _Float16* __restrict__ AO,
    const float* __restrict__ W, const float* __restrict__ bias,
    const float* __restrict__ Xin, float* __restrict__ Y) {
  __shared__ float ps[7][32 * 17];
  int t    = threadIdx.x;
  int li   = t & 31;
  int cg   = t >> 5;                            // 0..7: cc eighth (32 cc)
  int bx   = blockIdx.x;                        // 1024 blocks: b*2half*64lt
  int lt   = bx & 63;
  int half = (bx >> 6) & 1;
  int b    = bx >> 7;
  int l    = lt * 32 + li;
  const _Float16* ap = AO + (size_t)b * CHH * LL + cg * 32 * (size_t)LL + l;
  float acc[16];
#pragma unroll
  for (int j = 0; j < 16; ++j) acc[j] = 0.f;
  for (int cc = 0; cc < 32; cc += 4) {
    float a0 = (float)ap[(size_t)(cc + 0) * LL];
    float a1 = (float)ap[(size_t)(cc + 1) * LL];
    float a2 = (float)ap[(size_t)(cc + 2) * LL];
    float a3 = (float)ap[(size_t)(cc + 3) * LL];
#pragma unroll
    for (int j = 0; j < 16; ++j) {
      const float* wr = W + (half * 16 + j) * CHH + cg * 32 + cc;
      acc[j] = fmaf(wr[0], a0, acc[j]);
      acc[j] = fmaf(wr[1], a1, acc[j]);
      acc[j] = fmaf(wr[2], a2, acc[j]);
      acc[j] = fmaf(wr[3], a3, acc[j]);
    }
  }
  if (cg) {
#pragma unroll
    for (int j = 0; j < 16; ++j) ps[cg - 1][li * 17 + j] = acc[j];
  }
  __syncthreads();
  if (!cg) {                                    // threads 0..31
#pragma unroll
    for (int j = 0; j < 16; ++j) {
      int c = half * 16 + j;
      size_t o = ((size_t)b * CC + c) * LL + l;
      float r = acc[j] + bias[c] + Xin[o];
#pragma unroll
      for (int q = 0; q < 7; ++q) r += ps[q][li * 17 + j];
      Y[o] = r;
    }
  }
}

// ---------------------------------------------------------- instance norm
// (R10-verified form: 512 threads, 4 elems/thread.)
__global__ __launch_bounds__(512) void k_inorm(const float* __restrict__ Y,
    float* __restrict__ X, const float* __restrict__ g,
    const float* __restrict__ bt) {
  __shared__ float red[16];
  int row = blockIdx.x;
  int c = row & 31;
  const float* y = Y + (size_t)row * LL;
  float v[4];
  float s = 0.f, ss = 0.f;
#pragma unroll
  for (int i = 0; i < 4; ++i) {
    v[i] = y[threadIdx.x + 512 * i];
    s += v[i];
    ss = fmaf(v[i], v[i], ss);
  }
#pragma unroll
  for (int off = 32; off; off >>= 1) {
    s  += __shfl_down(s, off);
    ss += __shfl_down(ss, off);
  }
  int wid = threadIdx.x >> 6;
  if ((threadIdx.x & 63) == 0) { red[wid * 2] = s; red[wid * 2 + 1] = ss; }
  __syncthreads();
  if (threadIdx.x == 0) {
    float rs0 = 0.f, rs1 = 0.f;
#pragma unroll
    for (int i = 0; i < 8; ++i) { rs0 += red[i * 2]; rs1 += red[i * 2 + 1]; }
    red[0] = rs0; red[1] = rs1;
  }
  __syncthreads();
  float mean = red[0] * (1.f / LL);
  float var  = red[1] * (1.f / LL) - mean * mean;
  float rs = rsqrtf(var + 1e-5f) * g[c];
  float bb = bt[c];
#pragma unroll
  for (int i = 0; i < 4; ++i)
    X[(size_t)row * LL + threadIdx.x + 512 * i] = (v[i] - mean) * rs + bb;
}

// -------- fused FFN v5 (R10-verified): LDS-staged weights, phase-split.
// LDS: wlds 33.3KB + ps 29.6KB = 62.8KB -> 2 blocks/CU.
__global__ __launch_bounds__(256) void k_ffn(const float* __restrict__ X,
    const float* __restrict__ W1, const float* __restrict__ b1,
    const float* __restrict__ W2, const float* __restrict__ b2,
    float* __restrict__ Y) {
  __shared__ __align__(16) float wlds[8320];    // W1 @0, W2 @4096, b1 @8192
  __shared__ float ps[7][32 * 33];
  int bx = blockIdx.x;                          // 8b * 64lt
  int b = bx >> 6;
  int l0 = (bx & 63) * 32;
  int t = threadIdx.x;
  int li = t & 31;
  int og = t >> 5;                              // 0..7
  int l = l0 + li;
  // ---- stage weights to LDS (coalesced f4)
#pragma unroll
  for (int i = 0; i < 4; ++i)
    ((f4*)wlds)[t + i * 256] = ((const f4*)W1)[t + i * 256];
#pragma unroll
  for (int i = 0; i < 4; ++i)
    ((f4*)(wlds + 4096))[t + i * 256] = ((const f4*)W2)[t + i * 256];
  if (t < 32) ((f4*)(wlds + 8192))[t] = ((const f4*)b1)[t];

  const float* Xp = X + (size_t)b * CC * LL + l;
  float xv[32];
#pragma unroll
  for (int c = 0; c < 32; ++c) xv[c] = Xp[(size_t)c * LL];
  __syncthreads();

  // ---- phase A: 16 hidden units, 4-wide partial chains from LDS
  float hs[16];
#pragma unroll
  for (int op = 0; op < 16; ++op) {
    int o = og * 16 + op;
    const f4* wr = (const f4*)(wlds + o * 32);
    f4 p = {wlds[8192 + o], 0.f, 0.f, 0.f};
#pragma unroll
    for (int c4 = 0; c4 < 8; ++c4) {
      f4 a = wr[c4];
      p[0] = fmaf(a[0], xv[c4 * 4 + 0], p[0]);
      p[1] = fmaf(a[1], xv[c4 * 4 + 1], p[1]);
      p[2] = fmaf(a[2], xv[c4 * 4 + 2], p[2]);
      p[3] = fmaf(a[3], xv[c4 * 4 + 3], p[3]);
    }
    hs[op] = fmaxf((p[0] + p[1]) + (p[2] + p[3]), 0.f);
  }

  // ---- phase B: 32 outputs, f4 W2 reads from LDS
  float acc[32];
#pragma unroll
  for (int c = 0; c < 32; ++c) {
    const f4* w2r = (const f4*)(wlds + 4096 + c * 128 + og * 16);
    f4 s = {0.f, 0.f, 0.f, 0.f};
#pragma unroll
    for (int o4 = 0; o4 < 4; ++o4) {
      f4 w = w2r[o4];
      s[0] = fmaf(w[0], hs[o4 * 4 + 0], s[0]);
      s[1] = fmaf(w[1], hs[o4 * 4 + 1], s[1]);
      s[2] = fmaf(w[2], hs[o4 * 4 + 2], s[2]);
      s[3] = fmaf(w[3], hs[o4 * 4 + 3], s[3]);
    }
    acc[c] = (s[0] + s[1]) + (s[2] + s[3]);
  }

  if (og) {
#pragma unroll
    for (int c = 0; c < 32; ++c) ps[og - 1][li * 33 + c] = acc[c];
  }
  __syncthreads();
  if (!og) {
    float* Yp = Y + (size_t)b * CC * LL + l;
#pragma unroll
    for (int c = 0; c < 32; ++c) {
      float r = acc[c] + b2[c] + xv[c];
#pragma unroll
      for (int q = 0; q < 7; ++q) r += ps[q][li * 33 + c];
      Yp[(size_t)c * LL] = r;
    }
  }
}

// ------------------------------------------------------------- classifier
__global__ __launch_bounds__(256) void k_cls(const float* __restrict__ X,
    const float* __restrict__ W, const float* __restrict__ bias,
    float* __restrict__ out) {
  int idx = blockIdx.x * 256 + threadIdx.x;
  int l = idx & (LL - 1);
  int b = idx >> 11;
  float s = bias[0];
#pragma unroll
  for (int c = 0; c < CC; ++c)
    s = fmaf(W[c], X[((size_t)b * CC + c) * LL + l], s);
  out[idx] = 1.f / (1.f + __expf(-s));
}

// ------------------------------------------------------------------ launch
extern "C" void kernel_launch(void* const* d_in, const int* in_sizes, int n_in,
                              void* d_out, int out_size, void* d_ws,
                              size_t ws_size, hipStream_t stream) {
  const float* x      = (const float*)d_in[0];
  const float* enc_W  = (const float*)d_in[1];
  const float* enc_b  = (const float*)d_in[2];
  const float* pw_q   = (const float*)d_in[3];
  const float* dw3_q  = (const float*)d_in[4];
  const float* dw15_q = (const float*)d_in[5];
  const float* gate_q = (const float*)d_in[6];
  const float* pw_k   = (const float*)d_in[7];
  const float* dw3_k  = (const float*)d_in[8];
  const float* dw15_k = (const float*)d_in[9];
  const float* gate_k = (const float*)d_in[10];
  const float* pw_v   = (const float*)d_in[11];
  const float* dw3_v  = (const float*)d_in[12];
  const float* dw15_v = (const float*)d_in[13];
  const float* gate_v = (const float*)d_in[14];
  const float* uni_W  = (const float*)d_in[15];
  const float* uni_b  = (const float*)d_in[16];
  const float* n1_g   = (const float*)d_in[17];
  const float* n1_b   = (const float*)d_in[18];
  const float* n2_g   = (const float*)d_in[19];
  const float* n2_b   = (const float*)d_in[20];
  const float* ffn_W1 = (const float*)d_in[21];
  const float* ffn_b1 = (const float*)d_in[22];
  const float* ffn_W2 = (const float*)d_in[23];
  const float* ffn_b2 = (const float*)d_in[24];
  const float* cls_W  = (const float*)d_in[25];
  const float* cls_b  = (const float*)d_in[26];

  float* ws = (float*)d_ws;
  float* X   = ws;                             // [B,32,L] fp32
  float* Y   = ws + 524288;                    // [B,32,L] fp32
  _Float16* AO = (_Float16*)(ws + 1048576);    // [B,256,L] f16 attn out
  _Float16* Qt = (_Float16*)(ws + 9437184);    // [64bh][L][32c] f16
  _Float16* Kt = (_Float16*)(ws + 11534336);   // [64bh][L][32c] f16
  _Float16* Vt = (_Float16*)(ws + 13631488);   // [64bh][32c][L] f16

  k_enc<<<2048, 256, 0, stream>>>(x, enc_W, enc_b, X);

  for (int d = 0; d < DD; ++d) {
    k_qkv<<<dim3(1024, 3), 256, 0, stream>>>(X,
        pw_q + d * CHH * CC, pw_k + d * CHH * CC, pw_v + d * CHH * CC,
        dw3_q + d * CHH * 3, dw15_q + d * CHH * 15, gate_q + d * 2,
        dw3_k + d * CHH * 3, dw15_k + d * CHH * 15, gate_k + d * 2,
        dw3_v + d * CHH * 3, dw15_v + d * CHH * 15, gate_v + d * 2,
        Qt, Kt, Vt);
    k_attn<<<dim3(16, 64), 512, 0, stream>>>(Qt, Kt, Vt, AO);
    k_uni_res<<<1024, 256, 0, stream>>>(AO, uni_W + d * CC * CHH,
                                        uni_b + d * CC, X, Y);
    k_inorm<<<256, 512, 0, stream>>>(Y, X, n1_g + d * CC, n1_b + d * CC);
    k_ffn<<<512, 256, 0, stream>>>(X, ffn_W1 + d * 128 * CC, ffn_b1 + d * 128,
                                   ffn_W2 + d * CC * 128, ffn_b2 + d * CC, Y);
    k_inorm<<<256, 512, 0, stream>>>(Y, X, n2_g + d * CC, n2_b + d * CC);
  }

  k_cls<<<64, 256, 0, stream>>>(X, cls_W, cls_b, (float*)d_out);
}

// Round 16
// 746.690 us; speedup vs baseline: 1.2191x; 1.1822x over previous
//
#include <hip/hip_runtime.h>
#include <math.h>

#define LL   2048
#define BB   8
#define CC   32
#define CHH  256
#define HH   8
#define DD   6

typedef _Float16 h8 __attribute__((ext_vector_type(8)));
typedef _Float16 h4 __attribute__((ext_vector_type(4)));
typedef float f4 __attribute__((ext_vector_type(4)));
typedef float f2v __attribute__((ext_vector_type(2)));

// ---------------------------------------------------------------- encoder
__global__ __launch_bounds__(256) void k_enc(const float* __restrict__ x,
    const float* __restrict__ W, const float* __restrict__ bias,
    float* __restrict__ X) {
  int idx = blockIdx.x * 256 + threadIdx.x;          // B*32*L = 524288
  int l = idx & (LL - 1);
  int c = (idx >> 11) & 31;
  int b = idx >> 16;
  float s = bias[c];
#pragma unroll
  for (int i = 0; i < 6; ++i)
    s = fmaf(W[c * 6 + i], x[((size_t)b * 6 + i) * LL + l], s);
  X[idx] = s;
}

// ------------- fused QKV v2: MFMA pointwise conv + depthwise conv3/conv15 +
// gate + cvt + layout. R16: phase 1 was issue-bound (320 LDS ops/thread for
// 576 FMAs, 32x144x32 GEMM on scalar VALU). Now 18 mfma_f32_16x16x32_f16
// tiles (m=r 2 tiles, n=m-idx 9 tiles, k=ci): ~45 LDS ops/lane. X and W
// cast to f16 at staging (MFMA f32 accum; pw output was f16 anyway).
// LDS: Xh f16[32][152] @0 (9728) | Wh f16[32][32] @9728 (2048) |
// o_tile 32x304B @11776 -> 21504 total (was 32384; 4 -> 7 blocks/CU).
// Phase 2 (depthwise+gate+layout) unchanged; z<2 transpose reuses @0.
// grid (1024 = bh*16+lt, 3 z), 256 thr.
__global__ __launch_bounds__(256) void k_qkv(const float* __restrict__ X,
    const float* __restrict__ pwq, const float* __restrict__ pwk,
    const float* __restrict__ pwv,
    const float* __restrict__ d3q, const float* __restrict__ d15q, const float* __restrict__ gq,
    const float* __restrict__ d3k, const float* __restrict__ d15k, const float* __restrict__ gk,
    const float* __restrict__ d3v, const float* __restrict__ d15v, const float* __restrict__ gv,
    _Float16* __restrict__ Qt, _Float16* __restrict__ Kt, _Float16* __restrict__ Vt) {
  __shared__ __align__(16) char lds[21504];
  int z  = blockIdx.y;
  int bx = blockIdx.x;
  int bh = bx >> 4, lt = bx & 15, l0 = lt * 128;
  int b = bh >> 3, h = bh & 7;
  int t = threadIdx.x;
  const float* pwp  = (z == 0) ? pwq  : (z == 1) ? pwk  : pwv;
  const float* w3p  = (z == 0) ? d3q  : (z == 1) ? d3k  : d3v;
  const float* w15p = (z == 0) ? d15q : (z == 1) ? d15k : d15v;
  const float* gp   = (z == 0) ? gq   : (z == 1) ? gk   : gv;

  char* Xh = lds;                              // f16 [32 ci][152 m] rows 304B
  char* Wh = lds + 9728;                       // f16 [32 r][32 ci] rows 64B
  char* ot = lds + 11776;                      // pw out f16, 32 x 304B

  // ---- stage X -> f16 [ci][m], m = l-(l0-8) in [0,144), OOB zero
  {
    int r = t >> 3, u = t & 7;
    const float* xr = X + ((size_t)b * CC + r) * LL;
    char* xd = Xh + r * 304;
#pragma unroll
    for (int s = u; s < 36; s += 8) {
      int ls = l0 - 8 + s * 4;
      f4 v;
      if (ls >= 0 && ls + 3 < LL) {
        v = *(const f4*)(xr + ls);
      } else {
#pragma unroll
        for (int e = 0; e < 4; ++e) {
          int l = ls + e;
          v[e] = (l >= 0 && l < LL) ? xr[l] : 0.f;
        }
      }
      uint2 pk;
      pk.x = __builtin_bit_cast(unsigned, __builtin_amdgcn_cvt_pkrtz(v[0], v[1]));
      pk.y = __builtin_bit_cast(unsigned, __builtin_amdgcn_cvt_pkrtz(v[2], v[3]));
      *(uint2*)(xd + s * 8) = pk;
    }
  }
  // ---- stage W -> f16 [r][ci]
  {
    f4 wg = ((const f4*)(pwp + h * 1024))[t];  // och = t>>3, ci0 = (t&7)*4
    uint2 pk;
    pk.x = __builtin_bit_cast(unsigned, __builtin_amdgcn_cvt_pkrtz(wg[0], wg[1]));
    pk.y = __builtin_bit_cast(unsigned, __builtin_amdgcn_cvt_pkrtz(wg[2], wg[3]));
    *(uint2*)(Wh + (t >> 3) * 64 + (t & 7) * 8) = pk;
  }
  __syncthreads();

  // ---- phase 1: pointwise conv as MFMA.  out[r][m] = sum_ci W[r][ci]X[ci][m]
  {
    int w4 = t >> 6, lane = t & 63;
    int g = lane >> 4, ln = lane & 15;
    h8 af[2];
#pragma unroll
    for (int mt = 0; mt < 2; ++mt)
      af[mt] = *(const h8*)(Wh + (mt * 16 + ln) * 64 + g * 16);
    for (int nt = w4; nt < 9; nt += 4) {
      h8 bf;
#pragma unroll
      for (int j = 0; j < 8; ++j)
        bf[j] = *(const _Float16*)(Xh + (g * 8 + j) * 304 + (nt * 16 + ln) * 2);
#pragma unroll
      for (int mt = 0; mt < 2; ++mt) {
        f4 zr = {0.f, 0.f, 0.f, 0.f};
        f4 d = __builtin_amdgcn_mfma_f32_16x16x32_f16(af[mt], bf, zr, 0, 0, 0);
#pragma unroll
        for (int i = 0; i < 4; ++i)
          *(_Float16*)(ot + (mt * 16 + g * 4 + i) * 304 + (nt * 16 + ln) * 2) =
              (_Float16)d[i];
      }
    }
  }
  __syncthreads();

  // ---- phase 2: depthwise conv3 + conv15 + softmax gate (unchanged)
  int c = t & 31, cg = t >> 5;
  float wv[32];
  {
    const h8* wp = (const h8*)(ot + c * 304 + cg * 32);
#pragma unroll
    for (int q4 = 0; q4 < 4; ++q4) {
      h8 v = wp[q4];
#pragma unroll
      for (int e = 0; e < 8; ++e) wv[q4 * 8 + e] = (float)v[e];
    }
  }
  float r0 = gp[0], r1 = gp[1];
  float mx = fmaxf(r0, r1);
  float e0 = __expf(r0 - mx), e1 = __expf(r1 - mx);
  float gi = 1.f / (e0 + e1);
  float g0 = e0 * gi, g1 = e1 * gi;
  float sc = (z == 0) ? 0.2550765737f : 1.0f;   // C^-0.5 * log2(e) fold
  int ch = h * 32 + c;
  float w3r[3], w15r[15];
#pragma unroll
  for (int k = 0; k < 3; ++k)  w3r[k]  = w3p[ch * 3 + k];
#pragma unroll
  for (int k = 0; k < 15; ++k) w15r[k] = w15p[ch * 15 + k];

  h8 olo, ohi;
#pragma unroll
  for (int i = 0; i < 16; ++i) {
    float a = 0.f;
#pragma unroll
    for (int k = 0; k < 3; ++k) a = fmaf(w3r[k], wv[i + 7 + k], a);
    float s15 = 0.f;
#pragma unroll
    for (int k = 0; k < 15; ++k) s15 = fmaf(w15r[k], wv[i + 1 + k], s15);
    float val = (g0 * a + g1 * s15) * sc;
    if (i < 8) olo[i] = (_Float16)val; else ohi[i - 8] = (_Float16)val;
  }

  if (z == 2) {
    _Float16* dst = Vt + ((size_t)bh * 32 + c) * LL + l0 + cg * 16;
    *(h8*)dst = olo;
    *(h8*)(dst + 8) = ohi;
  } else {
    char* tb = lds;                             // reuse Xh region (dead)
    __syncthreads();                            // all phase-2 ot reads done?
    // NOTE: ot reads happened above; Xh region is dead since phase 1.
    // Barrier ensures no thread still reads Xh (none do) — kept for safety
    // against write-before-read of tb vs any straggler ot access in-wave.
#pragma unroll
    for (int i = 0; i < 16; ++i) {
      _Float16 v = (i < 8) ? olo[i] : ohi[i - 8];
      *(_Float16*)(tb + (cg * 16 + i) * 80 + c * 2) = v;
    }
    __syncthreads();
    _Float16* dst = ((z == 0) ? Qt : Kt) + ((size_t)bh * LL + l0) * 32;
    int l = t >> 1, hf = t & 1;
    uint4 a = *(uint4*)(tb + l * 80 + hf * 32);
    uint4 b2 = *(uint4*)(tb + l * 80 + hf * 32 + 16);
    *(uint4*)(dst + (size_t)l * 32 + hf * 16) = a;
    *(uint4*)(dst + (size_t)l * 32 + hf * 16 + 8) = b2;
  }
}

// ------------------------------------------------ MFMA flash attention (f16)
// R14-verified: XCD-aware block swizzle (FETCH 69.7->12.3 MB confirmed) +
// R4/R6 core: 8 waves, key-split, dbuf LDS, native exp2, permlane PV
// fragment, in-LDS merge.
__global__ __launch_bounds__(512, 2) void k_attn(
    const _Float16* __restrict__ Qt, const _Float16* __restrict__ Kt,
    const _Float16* __restrict__ Vt, _Float16* __restrict__ AO) {
  __shared__ __align__(16) char lds[38912];
  const int tid  = threadIdx.x;
  const int lane = tid & 63;
  const int w    = tid >> 6;                   // 0..7
  const int seg  = w >> 2;                     // 0..1: key segment
  const int wq   = w & 3;                      // q sub-block within 128
  const int g    = lane >> 4;
  const int ln   = lane & 15;
  const int h2c  = (wq >> 1) * 2;
  const int lin  = blockIdx.x + (blockIdx.y << 4);        // 0..1023
  const int swz  = ((lin & 7) << 7) | (lin >> 3);         // XCD-grouped
  const int qb   = swz & 15;                   // 0..15
  const int bh   = swz >> 4;                   // 0..63
  const _Float16* Qg = Qt + ((size_t)bh * LL + qb * 128) * 32;
  const _Float16* Kg = Kt + ((size_t)bh * LL + seg * 1024) * 32;
  const _Float16* Vg = Vt + (size_t)bh * 32 * LL + seg * 1024;

  h8 qf[2];
#pragma unroll
  for (int nt = 0; nt < 2; ++nt)
    qf[nt] = *(const h8*)(Qg + (size_t)(wq * 32 + nt * 16 + ln) * 32 + g * 8);

  h8 ones;
#pragma unroll
  for (int j = 0; j < 8; ++j) ones[j] = (_Float16)1.0f;

  char* kb = lds + seg * 5120;                 // + p*10240
  char* vb = lds + 20480 + seg * 4608;         // + p*9216

  uint4 stg0, stg1;
  if ((wq & 1) == 0) {
    const uint4* gk = (const uint4*)Kg;
    stg0 = gk[h2c * 64 + lane];
    stg1 = gk[(h2c + 1) * 64 + lane];
    *(uint4*)(kb + (h2c * 16 + (lane >> 2)) * 80 + (lane & 3) * 16) = stg0;
    *(uint4*)(kb + ((h2c + 1) * 16 + (lane >> 2)) * 80 + (lane & 3) * 16) = stg1;
  } else {
    int c0 = h2c * 8 + (lane >> 3);
    stg0 = *(const uint4*)(Vg + (size_t)c0 * LL + (lane & 7) * 8);
    stg1 = *(const uint4*)(Vg + (size_t)(c0 + 8) * LL + (lane & 7) * 8);
    *(uint4*)(vb + c0 * 144 + (lane & 7) * 16) = stg0;
    *(uint4*)(vb + (c0 + 8) * 144 + (lane & 7) * 16) = stg1;
  }
  __syncthreads();

  f4 o[2][2];
#pragma unroll
  for (int ct = 0; ct < 2; ++ct)
#pragma unroll
    for (int nt = 0; nt < 2; ++nt) o[ct][nt] = (f4){0.f, 0.f, 0.f, 0.f};
  f4 sacc[2];
#pragma unroll
  for (int nt = 0; nt < 2; ++nt) sacc[nt] = (f4){0.f, 0.f, 0.f, 0.f};

  for (int it = 0; it < 16; ++it) {
    int pp = it & 1;
    char* kbc = kb + pp * 10240;
    char* vbc = vb + pp * 9216;
    if (it < 15) {
      int k0n = (it + 1) * 64;
      if ((wq & 1) == 0) {
        const uint4* gk = (const uint4*)(Kg + (size_t)k0n * 32);
        stg0 = gk[h2c * 64 + lane];
        stg1 = gk[(h2c + 1) * 64 + lane];
      } else {
        int c0 = h2c * 8 + (lane >> 3);
        stg0 = *(const uint4*)(Vg + (size_t)c0 * LL + k0n + (lane & 7) * 8);
        stg1 = *(const uint4*)(Vg + (size_t)(c0 + 8) * LL + k0n + (lane & 7) * 8);
      }
    }
#pragma unroll
    for (int chunk = 0; chunk < 2; ++chunk) {
      unsigned pa[2][2], pb[2][2];
#pragma unroll
      for (int mt2 = 0; mt2 < 2; ++mt2) {
        h8 kf = *(const h8*)(kbc + ((chunk * 2 + mt2) * 16 + ln) * 80 + g * 16);
#pragma unroll
        for (int nt = 0; nt < 2; ++nt) {
          f4 z = {0.f, 0.f, 0.f, 0.f};
          f4 s = __builtin_amdgcn_mfma_f32_16x16x32_f16(kf, qf[nt], z, 0, 0, 0);
          float p0 = __builtin_amdgcn_exp2f(s[0]);
          float p1 = __builtin_amdgcn_exp2f(s[1]);
          float p2 = __builtin_amdgcn_exp2f(s[2]);
          float p3 = __builtin_amdgcn_exp2f(s[3]);
          unsigned lo = __builtin_bit_cast(unsigned,
              __builtin_amdgcn_cvt_pkrtz(p0, p1));
          unsigned hi = __builtin_bit_cast(unsigned,
              __builtin_amdgcn_cvt_pkrtz(p2, p3));
          if (mt2 == 0) { pa[nt][0] = lo; pa[nt][1] = hi; }
          else          { pb[nt][0] = lo; pb[nt][1] = hi; }
        }
      }
      h8 vf[2];
#pragma unroll
      for (int ct = 0; ct < 2; ++ct)
        vf[ct] = *(const h8*)(vbc + (ct * 16 + ln) * 144 + chunk * 64 + g * 16);
#pragma unroll
      for (int nt = 0; nt < 2; ++nt) {
        unsigned w0 = pa[nt][0], w1 = pa[nt][1];
        unsigned w2 = pb[nt][0], w3 = pb[nt][1];
        asm("v_permlane32_swap_b32 %0, %1" : "+v"(w0), "+v"(w2));
        asm("v_permlane16_swap_b32 %0, %1" : "+v"(w0), "+v"(w2));
        asm("v_permlane32_swap_b32 %0, %1" : "+v"(w1), "+v"(w3));
        asm("v_permlane16_swap_b32 %0, %1" : "+v"(w1), "+v"(w3));
        uint4 pw4; pw4.x = w0; pw4.y = w1; pw4.z = w2; pw4.w = w3;
        h8 pf = __builtin_bit_cast(h8, pw4);
        sacc[nt] = __builtin_amdgcn_mfma_f32_16x16x32_f16(ones, pf, sacc[nt], 0, 0, 0);
        o[0][nt] = __builtin_amdgcn_mfma_f32_16x16x32_f16(vf[0], pf, o[0][nt], 0, 0, 0);
        o[1][nt] = __builtin_amdgcn_mfma_f32_16x16x32_f16(vf[1], pf, o[1][nt], 0, 0, 0);
      }
    }
    if (it < 15) {
      char* kbn = kb + (pp ^ 1) * 10240;
      char* vbn = vb + (pp ^ 1) * 9216;
      if ((wq & 1) == 0) {
        *(uint4*)(kbn + (h2c * 16 + (lane >> 2)) * 80 + (lane & 3) * 16) = stg0;
        *(uint4*)(kbn + ((h2c + 1) * 16 + (lane >> 2)) * 80 + (lane & 3) * 16) = stg1;
      } else {
        int c0 = h2c * 8 + (lane >> 3);
        *(uint4*)(vbn + c0 * 144 + (lane & 7) * 16) = stg0;
        *(uint4*)(vbn + (c0 + 8) * 144 + (lane & 7) * 16) = stg1;
      }
    }
    __syncthreads();
  }

  if (seg == 1) {
    char* eo = lds + wq * 9216 + lane * 144;
#pragma unroll
    for (int nt = 0; nt < 2; ++nt)
#pragma unroll
      for (int ct = 0; ct < 2; ++ct)
        *(f4*)(eo + (nt * 2 + ct) * 16) = o[ct][nt];
    f4 sv;
    sv[0] = sacc[0][0]; sv[1] = sacc[1][0];
    sv[2] = 0.f; sv[3] = 0.f;
    *(f4*)(eo + 64) = sv;
  }
  __syncthreads();
  if (seg == 0) {
    const char* po = lds + wq * 9216 + lane * 144;
    f4 s1v = *(const f4*)(po + 64);
    _Float16* out = AO + (size_t)bh * (32 * LL);
#pragma unroll
    for (int nt = 0; nt < 2; ++nt) {
      float inv = 1.f / (sacc[nt][0] + s1v[nt]);
      int qg = qb * 128 + wq * 32 + nt * 16 + ln;
#pragma unroll
      for (int ct = 0; ct < 2; ++ct) {
        f4 o1 = *(const f4*)(po + (nt * 2 + ct) * 16);
#pragma unroll
        for (int r = 0; r < 4; ++r)
          out[(size_t)(ct * 16 + g * 4 + r) * LL + qg] =
              (_Float16)((o[ct][nt][r] + o1[r]) * inv);
      }
    }
  }
}

// -------- uni GEMM [32,256] f16-in + bias + residual, v5 (R15 form).
// grid 1024: 32-l tiles, cc-split 8 -> 4 blocks/CU, 16 waves/CU.
__global__ __launch_bounds__(256) void k_uni_res(const _Float16* __restrict__ AO,
    const float* __restrict__ W, const float* __restrict__ bias,
    const float* __restrict__ Xin, float* __restrict__ Y) {
  __shared__ float ps[7][32 * 17];
  int t    = threadIdx.x;
  int li   = t & 31;
  int cg   = t >> 5;                            // 0..7: cc eighth (32 cc)
  int bx   = blockIdx.x;                        // 1024 blocks: b*2half*64lt
  int lt   = bx & 63;
  int half = (bx >> 6) & 1;
  int b    = bx >> 7;
  int l    = lt * 32 + li;
  const _Float16* ap = AO + (size_t)b * CHH * LL + cg * 32 * (size_t)LL + l;
  float acc[16];
#pragma unroll
  for (int j = 0; j < 16; ++j) acc[j] = 0.f;
  for (int cc = 0; cc < 32; cc += 4) {
    float a0 = (float)ap[(size_t)(cc + 0) * LL];
    float a1 = (float)ap[(size_t)(cc + 1) * LL];
    float a2 = (float)ap[(size_t)(cc + 2) * LL];
    float a3 = (float)ap[(size_t)(cc + 3) * LL];
#pragma unroll
    for (int j = 0; j < 16; ++j) {
      const float* wr = W + (half * 16 + j) * CHH + cg * 32 + cc;
      acc[j] = fmaf(wr[0], a0, acc[j]);
      acc[j] = fmaf(wr[1], a1, acc[j]);
      acc[j] = fmaf(wr[2], a2, acc[j]);
      acc[j] = fmaf(wr[3], a3, acc[j]);
    }
  }
  if (cg) {
#pragma unroll
    for (int j = 0; j < 16; ++j) ps[cg - 1][li * 17 + j] = acc[j];
  }
  __syncthreads();
  if (!cg) {                                    // threads 0..31
#pragma unroll
    for (int j = 0; j < 16; ++j) {
      int c = half * 16 + j;
      size_t o = ((size_t)b * CC + c) * LL + l;
      float r = acc[j] + bias[c] + Xin[o];
#pragma unroll
      for (int q = 0; q < 7; ++q) r += ps[q][li * 17 + j];
      Y[o] = r;
    }
  }
}

// ---------------------------------------------------------- instance norm
// (R10-verified form: 512 threads, 4 elems/thread.)
__global__ __launch_bounds__(512) void k_inorm(const float* __restrict__ Y,
    float* __restrict__ X, const float* __restrict__ g,
    const float* __restrict__ bt) {
  __shared__ float red[16];
  int row = blockIdx.x;
  int c = row & 31;
  const float* y = Y + (size_t)row * LL;
  float v[4];
  float s = 0.f, ss = 0.f;
#pragma unroll
  for (int i = 0; i < 4; ++i) {
    v[i] = y[threadIdx.x + 512 * i];
    s += v[i];
    ss = fmaf(v[i], v[i], ss);
  }
#pragma unroll
  for (int off = 32; off; off >>= 1) {
    s  += __shfl_down(s, off);
    ss += __shfl_down(ss, off);
  }
  int wid = threadIdx.x >> 6;
  if ((threadIdx.x & 63) == 0) { red[wid * 2] = s; red[wid * 2 + 1] = ss; }
  __syncthreads();
  if (threadIdx.x == 0) {
    float rs0 = 0.f, rs1 = 0.f;
#pragma unroll
    for (int i = 0; i < 8; ++i) { rs0 += red[i * 2]; rs1 += red[i * 2 + 1]; }
    red[0] = rs0; red[1] = rs1;
  }
  __syncthreads();
  float mean = red[0] * (1.f / LL);
  float var  = red[1] * (1.f / LL) - mean * mean;
  float rs = rsqrtf(var + 1e-5f) * g[c];
  float bb = bt[c];
#pragma unroll
  for (int i = 0; i < 4; ++i)
    X[(size_t)row * LL + threadIdx.x + 512 * i] = (v[i] - mean) * rs + bb;
}

// -------- fused FFN v5 (R10-verified): LDS-staged weights, phase-split.
// LDS: wlds 33.3KB + ps 29.6KB = 62.8KB -> 2 blocks/CU.
__global__ __launch_bounds__(256) void k_ffn(const float* __restrict__ X,
    const float* __restrict__ W1, const float* __restrict__ b1,
    const float* __restrict__ W2, const float* __restrict__ b2,
    float* __restrict__ Y) {
  __shared__ __align__(16) float wlds[8320];    // W1 @0, W2 @4096, b1 @8192
  __shared__ float ps[7][32 * 33];
  int bx = blockIdx.x;                          // 8b * 64lt
  int b = bx >> 6;
  int l0 = (bx & 63) * 32;
  int t = threadIdx.x;
  int li = t & 31;
  int og = t >> 5;                              // 0..7
  int l = l0 + li;
  // ---- stage weights to LDS (coalesced f4)
#pragma unroll
  for (int i = 0; i < 4; ++i)
    ((f4*)wlds)[t + i * 256] = ((const f4*)W1)[t + i * 256];
#pragma unroll
  for (int i = 0; i < 4; ++i)
    ((f4*)(wlds + 4096))[t + i * 256] = ((const f4*)W2)[t + i * 256];
  if (t < 32) ((f4*)(wlds + 8192))[t] = ((const f4*)b1)[t];

  const float* Xp = X + (size_t)b * CC * LL + l;
  float xv[32];
#pragma unroll
  for (int c = 0; c < 32; ++c) xv[c] = Xp[(size_t)c * LL];
  __syncthreads();

  // ---- phase A: 16 hidden units, 4-wide partial chains from LDS
  float hs[16];
#pragma unroll
  for (int op = 0; op < 16; ++op) {
    int o = og * 16 + op;
    const f4* wr = (const f4*)(wlds + o * 32);
    f4 p = {wlds[8192 + o], 0.f, 0.f, 0.f};
#pragma unroll
    for (int c4 = 0; c4 < 8; ++c4) {
      f4 a = wr[c4];
      p[0] = fmaf(a[0], xv[c4 * 4 + 0], p[0]);
      p[1] = fmaf(a[1], xv[c4 * 4 + 1], p[1]);
      p[2] = fmaf(a[2], xv[c4 * 4 + 2], p[2]);
      p[3] = fmaf(a[3], xv[c4 * 4 + 3], p[3]);
    }
    hs[op] = fmaxf((p[0] + p[1]) + (p[2] + p[3]), 0.f);
  }

  // ---- phase B: 32 outputs, f4 W2 reads from LDS
  float acc[32];
#pragma unroll
  for (int c = 0; c < 32; ++c) {
    const f4* w2r = (const f4*)(wlds + 4096 + c * 128 + og * 16);
    f4 s = {0.f, 0.f, 0.f, 0.f};
#pragma unroll
    for (int o4 = 0; o4 < 4; ++o4) {
      f4 w = w2r[o4];
      s[0] = fmaf(w[0], hs[o4 * 4 + 0], s[0]);
      s[1] = fmaf(w[1], hs[o4 * 4 + 1], s[1]);
      s[2] = fmaf(w[2], hs[o4 * 4 + 2], s[2]);
      s[3] = fmaf(w[3], hs[o4 * 4 + 3], s[3]);
    }
    acc[c] = (s[0] + s[1]) + (s[2] + s[3]);
  }

  if (og) {
#pragma unroll
    for (int c = 0; c < 32; ++c) ps[og - 1][li * 33 + c] = acc[c];
  }
  __syncthreads();
  if (!og) {
    float* Yp = Y + (size_t)b * CC * LL + l;
#pragma unroll
    for (int c = 0; c < 32; ++c) {
      float r = acc[c] + b2[c] + xv[c];
#pragma unroll
      for (int q = 0; q < 7; ++q) r += ps[q][li * 33 + c];
      Yp[(size_t)c * LL] = r;
    }
  }
}

// ------------------------------------------------------------- classifier
__global__ __launch_bounds__(256) void k_cls(const float* __restrict__ X,
    const float* __restrict__ W, const float* __restrict__ bias,
    float* __restrict__ out) {
  int idx = blockIdx.x * 256 + threadIdx.x;
  int l = idx & (LL - 1);
  int b = idx >> 11;
  float s = bias[0];
#pragma unroll
  for (int c = 0; c < CC; ++c)
    s = fmaf(W[c], X[((size_t)b * CC + c) * LL + l], s);
  out[idx] = 1.f / (1.f + __expf(-s));
}

// ------------------------------------------------------------------ launch
extern "C" void kernel_launch(void* const* d_in, const int* in_sizes, int n_in,
                              void* d_out, int out_size, void* d_ws,
                              size_t ws_size, hipStream_t stream) {
  const float* x      = (const float*)d_in[0];
  const float* enc_W  = (const float*)d_in[1];
  const float* enc_b  = (const float*)d_in[2];
  const float* pw_q   = (const float*)d_in[3];
  const float* dw3_q  = (const float*)d_in[4];
  const float* dw15_q = (const float*)d_in[5];
  const float* gate_q = (const float*)d_in[6];
  const float* pw_k   = (const float*)d_in[7];
  const float* dw3_k  = (const float*)d_in[8];
  const float* dw15_k = (const float*)d_in[9];
  const float* gate_k = (const float*)d_in[10];
  const float* pw_v   = (const float*)d_in[11];
  const float* dw3_v  = (const float*)d_in[12];
  const float* dw15_v = (const float*)d_in[13];
  const float* gate_v = (const float*)d_in[14];
  const float* uni_W  = (const float*)d_in[15];
  const float* uni_b  = (const float*)d_in[16];
  const float* n1_g   = (const float*)d_in[17];
  const float* n1_b   = (const float*)d_in[18];
  const float* n2_g   = (const float*)d_in[19];
  const float* n2_b   = (const float*)d_in[20];
  const float* ffn_W1 = (const float*)d_in[21];
  const float* ffn_b1 = (const float*)d_in[22];
  const float* ffn_W2 = (const float*)d_in[23];
  const float* ffn_b2 = (const float*)d_in[24];
  const float* cls_W  = (const float*)d_in[25];
  const float* cls_b  = (const float*)d_in[26];

  float* ws = (float*)d_ws;
  float* X   = ws;                             // [B,32,L] fp32
  float* Y   = ws + 524288;                    // [B,32,L] fp32
  _Float16* AO = (_Float16*)(ws + 1048576);    // [B,256,L] f16 attn out
  _Float16* Qt = (_Float16*)(ws + 9437184);    // [64bh][L][32c] f16
  _Float16* Kt = (_Float16*)(ws + 11534336);   // [64bh][L][32c] f16
  _Float16* Vt = (_Float16*)(ws + 13631488);   // [64bh][32c][L] f16

  k_enc<<<2048, 256, 0, stream>>>(x, enc_W, enc_b, X);

  for (int d = 0; d < DD; ++d) {
    k_qkv<<<dim3(1024, 3), 256, 0, stream>>>(X,
        pw_q + d * CHH * CC, pw_k + d * CHH * CC, pw_v + d * CHH * CC,
        dw3_q + d * CHH * 3, dw15_q + d * CHH * 15, gate_q + d * 2,
        dw3_k + d * CHH * 3, dw15_k + d * CHH * 15, gate_k + d * 2,
        dw3_v + d * CHH * 3, dw15_v + d * CHH * 15, gate_v + d * 2,
        Qt, Kt, Vt);
    k_attn<<<dim3(16, 64), 512, 0, stream>>>(Qt, Kt, Vt, AO);
    k_uni_res<<<1024, 256, 0, stream>>>(AO, uni_W + d * CC * CHH,
                                        uni_b + d * CC, X, Y);
    k_inorm<<<256, 512, 0, stream>>>(Y, X, n1_g + d * CC, n1_b + d * CC);
    k_ffn<<<512, 256, 0, stream>>>(X, ffn_W1 + d * 128 * CC, ffn_b1 + d * 128,
                                   ffn_W2 + d * CC * 128, ffn_b2 + d * CC, Y);
    k_inorm<<<256, 512, 0, stream>>>(Y, X, n2_g + d * CC, n2_b + d * CC);
  }

  k_cls<<<64, 256, 0, stream>>>(X, cls_W, cls_b, (float*)d_out);
}

// Round 17
// 663.386 us; speedup vs baseline: 1.3721x; 1.1256x over previous
//
#include <hip/hip_runtime.h>
#include <math.h>

#define LL   2048
#define BB   8
#define CC   32
#define CHH  256
#define HH   8
#define DD   6

typedef _Float16 h8 __attribute__((ext_vector_type(8)));
typedef _Float16 h4 __attribute__((ext_vector_type(4)));
typedef float f4 __attribute__((ext_vector_type(4)));
typedef float f2v __attribute__((ext_vector_type(2)));

// ---------------------------------------------------------------- encoder
__global__ __launch_bounds__(256) void k_enc(const float* __restrict__ x,
    const float* __restrict__ W, const float* __restrict__ bias,
    float* __restrict__ X) {
  int idx = blockIdx.x * 256 + threadIdx.x;          // B*32*L = 524288
  int l = idx & (LL - 1);
  int c = (idx >> 11) & 31;
  int b = idx >> 16;
  float s = bias[c];
#pragma unroll
  for (int i = 0; i < 6; ++i)
    s = fmaf(W[c * 6 + i], x[((size_t)b * 6 + i) * LL + l], s);
  X[idx] = s;
}

// ------------- fused QKV v2 (R16-verified): MFMA pointwise conv + depthwise
// conv3/conv15 + gate + cvt + layout. 18 mfma 16x16x32 tiles; ~45 LDS
// ops/lane (was 320). LDS: Xh @0 | Wh @9728 | o_tile @11776 -> 21504.
// grid (1024 = bh*16+lt, 3 z), 256 thr.
__global__ __launch_bounds__(256) void k_qkv(const float* __restrict__ X,
    const float* __restrict__ pwq, const float* __restrict__ pwk,
    const float* __restrict__ pwv,
    const float* __restrict__ d3q, const float* __restrict__ d15q, const float* __restrict__ gq,
    const float* __restrict__ d3k, const float* __restrict__ d15k, const float* __restrict__ gk,
    const float* __restrict__ d3v, const float* __restrict__ d15v, const float* __restrict__ gv,
    _Float16* __restrict__ Qt, _Float16* __restrict__ Kt, _Float16* __restrict__ Vt) {
  __shared__ __align__(16) char lds[21504];
  int z  = blockIdx.y;
  int bx = blockIdx.x;
  int bh = bx >> 4, lt = bx & 15, l0 = lt * 128;
  int b = bh >> 3, h = bh & 7;
  int t = threadIdx.x;
  const float* pwp  = (z == 0) ? pwq  : (z == 1) ? pwk  : pwv;
  const float* w3p  = (z == 0) ? d3q  : (z == 1) ? d3k  : d3v;
  const float* w15p = (z == 0) ? d15q : (z == 1) ? d15k : d15v;
  const float* gp   = (z == 0) ? gq   : (z == 1) ? gk   : gv;

  char* Xh = lds;                              // f16 [32 ci][152 m] rows 304B
  char* Wh = lds + 9728;                       // f16 [32 r][32 ci] rows 64B
  char* ot = lds + 11776;                      // pw out f16, 32 x 304B

  // ---- stage X -> f16 [ci][m], m = l-(l0-8) in [0,144), OOB zero
  {
    int r = t >> 3, u = t & 7;
    const float* xr = X + ((size_t)b * CC + r) * LL;
    char* xd = Xh + r * 304;
#pragma unroll
    for (int s = u; s < 36; s += 8) {
      int ls = l0 - 8 + s * 4;
      f4 v;
      if (ls >= 0 && ls + 3 < LL) {
        v = *(const f4*)(xr + ls);
      } else {
#pragma unroll
        for (int e = 0; e < 4; ++e) {
          int l = ls + e;
          v[e] = (l >= 0 && l < LL) ? xr[l] : 0.f;
        }
      }
      uint2 pk;
      pk.x = __builtin_bit_cast(unsigned, __builtin_amdgcn_cvt_pkrtz(v[0], v[1]));
      pk.y = __builtin_bit_cast(unsigned, __builtin_amdgcn_cvt_pkrtz(v[2], v[3]));
      *(uint2*)(xd + s * 8) = pk;
    }
  }
  // ---- stage W -> f16 [r][ci]
  {
    f4 wg = ((const f4*)(pwp + h * 1024))[t];  // och = t>>3, ci0 = (t&7)*4
    uint2 pk;
    pk.x = __builtin_bit_cast(unsigned, __builtin_amdgcn_cvt_pkrtz(wg[0], wg[1]));
    pk.y = __builtin_bit_cast(unsigned, __builtin_amdgcn_cvt_pkrtz(wg[2], wg[3]));
    *(uint2*)(Wh + (t >> 3) * 64 + (t & 7) * 8) = pk;
  }
  __syncthreads();

  // ---- phase 1: pointwise conv as MFMA.  out[r][m] = sum_ci W[r][ci]X[ci][m]
  {
    int w4 = t >> 6, lane = t & 63;
    int g = lane >> 4, ln = lane & 15;
    h8 af[2];
#pragma unroll
    for (int mt = 0; mt < 2; ++mt)
      af[mt] = *(const h8*)(Wh + (mt * 16 + ln) * 64 + g * 16);
    for (int nt = w4; nt < 9; nt += 4) {
      h8 bf;
#pragma unroll
      for (int j = 0; j < 8; ++j)
        bf[j] = *(const _Float16*)(Xh + (g * 8 + j) * 304 + (nt * 16 + ln) * 2);
#pragma unroll
      for (int mt = 0; mt < 2; ++mt) {
        f4 zr = {0.f, 0.f, 0.f, 0.f};
        f4 d = __builtin_amdgcn_mfma_f32_16x16x32_f16(af[mt], bf, zr, 0, 0, 0);
#pragma unroll
        for (int i = 0; i < 4; ++i)
          *(_Float16*)(ot + (mt * 16 + g * 4 + i) * 304 + (nt * 16 + ln) * 2) =
              (_Float16)d[i];
      }
    }
  }
  __syncthreads();

  // ---- phase 2: depthwise conv3 + conv15 + softmax gate (unchanged)
  int c = t & 31, cg = t >> 5;
  float wv[32];
  {
    const h8* wp = (const h8*)(ot + c * 304 + cg * 32);
#pragma unroll
    for (int q4 = 0; q4 < 4; ++q4) {
      h8 v = wp[q4];
#pragma unroll
      for (int e = 0; e < 8; ++e) wv[q4 * 8 + e] = (float)v[e];
    }
  }
  float r0 = gp[0], r1 = gp[1];
  float mx = fmaxf(r0, r1);
  float e0 = __expf(r0 - mx), e1 = __expf(r1 - mx);
  float gi = 1.f / (e0 + e1);
  float g0 = e0 * gi, g1 = e1 * gi;
  float sc = (z == 0) ? 0.2550765737f : 1.0f;   // C^-0.5 * log2(e) fold
  int ch = h * 32 + c;
  float w3r[3], w15r[15];
#pragma unroll
  for (int k = 0; k < 3; ++k)  w3r[k]  = w3p[ch * 3 + k];
#pragma unroll
  for (int k = 0; k < 15; ++k) w15r[k] = w15p[ch * 15 + k];

  h8 olo, ohi;
#pragma unroll
  for (int i = 0; i < 16; ++i) {
    float a = 0.f;
#pragma unroll
    for (int k = 0; k < 3; ++k) a = fmaf(w3r[k], wv[i + 7 + k], a);
    float s15 = 0.f;
#pragma unroll
    for (int k = 0; k < 15; ++k) s15 = fmaf(w15r[k], wv[i + 1 + k], s15);
    float val = (g0 * a + g1 * s15) * sc;
    if (i < 8) olo[i] = (_Float16)val; else ohi[i - 8] = (_Float16)val;
  }

  if (z == 2) {
    _Float16* dst = Vt + ((size_t)bh * 32 + c) * LL + l0 + cg * 16;
    *(h8*)dst = olo;
    *(h8*)(dst + 8) = ohi;
  } else {
    char* tb = lds;                             // reuse Xh region (dead)
    __syncthreads();
#pragma unroll
    for (int i = 0; i < 16; ++i) {
      _Float16 v = (i < 8) ? olo[i] : ohi[i - 8];
      *(_Float16*)(tb + (cg * 16 + i) * 80 + c * 2) = v;
    }
    __syncthreads();
    _Float16* dst = ((z == 0) ? Qt : Kt) + ((size_t)bh * LL + l0) * 32;
    int l = t >> 1, hf = t & 1;
    uint4 a = *(uint4*)(tb + l * 80 + hf * 32);
    uint4 b2 = *(uint4*)(tb + l * 80 + hf * 32 + 16);
    *(uint4*)(dst + (size_t)l * 32 + hf * 16) = a;
    *(uint4*)(dst + (size_t)l * 32 + hf * 16 + 8) = b2;
  }
}

// ------------------------------------------------ MFMA flash attention (f16)
// R14-verified: XCD-aware block swizzle (FETCH 69.7->12.3 MB confirmed) +
// R4/R6 core: 8 waves, key-split, dbuf LDS, native exp2, permlane PV
// fragment, in-LDS merge.
__global__ __launch_bounds__(512, 2) void k_attn(
    const _Float16* __restrict__ Qt, const _Float16* __restrict__ Kt,
    const _Float16* __restrict__ Vt, _Float16* __restrict__ AO) {
  __shared__ __align__(16) char lds[38912];
  const int tid  = threadIdx.x;
  const int lane = tid & 63;
  const int w    = tid >> 6;                   // 0..7
  const int seg  = w >> 2;                     // 0..1: key segment
  const int wq   = w & 3;                      // q sub-block within 128
  const int g    = lane >> 4;
  const int ln   = lane & 15;
  const int h2c  = (wq >> 1) * 2;
  const int lin  = blockIdx.x + (blockIdx.y << 4);        // 0..1023
  const int swz  = ((lin & 7) << 7) | (lin >> 3);         // XCD-grouped
  const int qb   = swz & 15;                   // 0..15
  const int bh   = swz >> 4;                   // 0..63
  const _Float16* Qg = Qt + ((size_t)bh * LL + qb * 128) * 32;
  const _Float16* Kg = Kt + ((size_t)bh * LL + seg * 1024) * 32;
  const _Float16* Vg = Vt + (size_t)bh * 32 * LL + seg * 1024;

  h8 qf[2];
#pragma unroll
  for (int nt = 0; nt < 2; ++nt)
    qf[nt] = *(const h8*)(Qg + (size_t)(wq * 32 + nt * 16 + ln) * 32 + g * 8);

  h8 ones;
#pragma unroll
  for (int j = 0; j < 8; ++j) ones[j] = (_Float16)1.0f;

  char* kb = lds + seg * 5120;                 // + p*10240
  char* vb = lds + 20480 + seg * 4608;         // + p*9216

  uint4 stg0, stg1;
  if ((wq & 1) == 0) {
    const uint4* gk = (const uint4*)Kg;
    stg0 = gk[h2c * 64 + lane];
    stg1 = gk[(h2c + 1) * 64 + lane];
    *(uint4*)(kb + (h2c * 16 + (lane >> 2)) * 80 + (lane & 3) * 16) = stg0;
    *(uint4*)(kb + ((h2c + 1) * 16 + (lane >> 2)) * 80 + (lane & 3) * 16) = stg1;
  } else {
    int c0 = h2c * 8 + (lane >> 3);
    stg0 = *(const uint4*)(Vg + (size_t)c0 * LL + (lane & 7) * 8);
    stg1 = *(const uint4*)(Vg + (size_t)(c0 + 8) * LL + (lane & 7) * 8);
    *(uint4*)(vb + c0 * 144 + (lane & 7) * 16) = stg0;
    *(uint4*)(vb + (c0 + 8) * 144 + (lane & 7) * 16) = stg1;
  }
  __syncthreads();

  f4 o[2][2];
#pragma unroll
  for (int ct = 0; ct < 2; ++ct)
#pragma unroll
    for (int nt = 0; nt < 2; ++nt) o[ct][nt] = (f4){0.f, 0.f, 0.f, 0.f};
  f4 sacc[2];
#pragma unroll
  for (int nt = 0; nt < 2; ++nt) sacc[nt] = (f4){0.f, 0.f, 0.f, 0.f};

  for (int it = 0; it < 16; ++it) {
    int pp = it & 1;
    char* kbc = kb + pp * 10240;
    char* vbc = vb + pp * 9216;
    if (it < 15) {
      int k0n = (it + 1) * 64;
      if ((wq & 1) == 0) {
        const uint4* gk = (const uint4*)(Kg + (size_t)k0n * 32);
        stg0 = gk[h2c * 64 + lane];
        stg1 = gk[(h2c + 1) * 64 + lane];
      } else {
        int c0 = h2c * 8 + (lane >> 3);
        stg0 = *(const uint4*)(Vg + (size_t)c0 * LL + k0n + (lane & 7) * 8);
        stg1 = *(const uint4*)(Vg + (size_t)(c0 + 8) * LL + k0n + (lane & 7) * 8);
      }
    }
#pragma unroll
    for (int chunk = 0; chunk < 2; ++chunk) {
      unsigned pa[2][2], pb[2][2];
#pragma unroll
      for (int mt2 = 0; mt2 < 2; ++mt2) {
        h8 kf = *(const h8*)(kbc + ((chunk * 2 + mt2) * 16 + ln) * 80 + g * 16);
#pragma unroll
        for (int nt = 0; nt < 2; ++nt) {
          f4 z = {0.f, 0.f, 0.f, 0.f};
          f4 s = __builtin_amdgcn_mfma_f32_16x16x32_f16(kf, qf[nt], z, 0, 0, 0);
          float p0 = __builtin_amdgcn_exp2f(s[0]);
          float p1 = __builtin_amdgcn_exp2f(s[1]);
          float p2 = __builtin_amdgcn_exp2f(s[2]);
          float p3 = __builtin_amdgcn_exp2f(s[3]);
          unsigned lo = __builtin_bit_cast(unsigned,
              __builtin_amdgcn_cvt_pkrtz(p0, p1));
          unsigned hi = __builtin_bit_cast(unsigned,
              __builtin_amdgcn_cvt_pkrtz(p2, p3));
          if (mt2 == 0) { pa[nt][0] = lo; pa[nt][1] = hi; }
          else          { pb[nt][0] = lo; pb[nt][1] = hi; }
        }
      }
      h8 vf[2];
#pragma unroll
      for (int ct = 0; ct < 2; ++ct)
        vf[ct] = *(const h8*)(vbc + (ct * 16 + ln) * 144 + chunk * 64 + g * 16);
#pragma unroll
      for (int nt = 0; nt < 2; ++nt) {
        unsigned w0 = pa[nt][0], w1 = pa[nt][1];
        unsigned w2 = pb[nt][0], w3 = pb[nt][1];
        asm("v_permlane32_swap_b32 %0, %1" : "+v"(w0), "+v"(w2));
        asm("v_permlane16_swap_b32 %0, %1" : "+v"(w0), "+v"(w2));
        asm("v_permlane32_swap_b32 %0, %1" : "+v"(w1), "+v"(w3));
        asm("v_permlane16_swap_b32 %0, %1" : "+v"(w1), "+v"(w3));
        uint4 pw4; pw4.x = w0; pw4.y = w1; pw4.z = w2; pw4.w = w3;
        h8 pf = __builtin_bit_cast(h8, pw4);
        sacc[nt] = __builtin_amdgcn_mfma_f32_16x16x32_f16(ones, pf, sacc[nt], 0, 0, 0);
        o[0][nt] = __builtin_amdgcn_mfma_f32_16x16x32_f16(vf[0], pf, o[0][nt], 0, 0, 0);
        o[1][nt] = __builtin_amdgcn_mfma_f32_16x16x32_f16(vf[1], pf, o[1][nt], 0, 0, 0);
      }
    }
    if (it < 15) {
      char* kbn = kb + (pp ^ 1) * 10240;
      char* vbn = vb + (pp ^ 1) * 9216;
      if ((wq & 1) == 0) {
        *(uint4*)(kbn + (h2c * 16 + (lane >> 2)) * 80 + (lane & 3) * 16) = stg0;
        *(uint4*)(kbn + ((h2c + 1) * 16 + (lane >> 2)) * 80 + (lane & 3) * 16) = stg1;
      } else {
        int c0 = h2c * 8 + (lane >> 3);
        *(uint4*)(vbn + c0 * 144 + (lane & 7) * 16) = stg0;
        *(uint4*)(vbn + (c0 + 8) * 144 + (lane & 7) * 16) = stg1;
      }
    }
    __syncthreads();
  }

  if (seg == 1) {
    char* eo = lds + wq * 9216 + lane * 144;
#pragma unroll
    for (int nt = 0; nt < 2; ++nt)
#pragma unroll
      for (int ct = 0; ct < 2; ++ct)
        *(f4*)(eo + (nt * 2 + ct) * 16) = o[ct][nt];
    f4 sv;
    sv[0] = sacc[0][0]; sv[1] = sacc[1][0];
    sv[2] = 0.f; sv[3] = 0.f;
    *(f4*)(eo + 64) = sv;
  }
  __syncthreads();
  if (seg == 0) {
    const char* po = lds + wq * 9216 + lane * 144;
    f4 s1v = *(const f4*)(po + 64);
    _Float16* out = AO + (size_t)bh * (32 * LL);
#pragma unroll
    for (int nt = 0; nt < 2; ++nt) {
      float inv = 1.f / (sacc[nt][0] + s1v[nt]);
      int qg = qb * 128 + wq * 32 + nt * 16 + ln;
#pragma unroll
      for (int ct = 0; ct < 2; ++ct) {
        f4 o1 = *(const f4*)(po + (nt * 2 + ct) * 16);
#pragma unroll
        for (int r = 0; r < 4; ++r)
          out[(size_t)(ct * 16 + g * 4 + r) * LL + qg] =
              (_Float16)((o[ct][nt][r] + o1[r]) * inv);
      }
    }
  }
}

// -------- uni GEMM v6: MFMA. out[c][l] = sum_cc W[c][cc]*AO[cc][l] + bias +
// residual. R17: same G10 lever that won R16 — per-batch 32x2048x256 GEMM
// was scalar VALU (latency-bound, ~15-20us/layer). Now: A = W cast f16
// (k=cc contiguous), B = AO^T staged via LDS transpose ([l][cc] rows),
// 8 k-steps of mfma 16x16x32 per wave, D-fragment epilogue.
// LDS rows padded to 560 B (16B-aligned; lane row-stride = 12 banks -> ~2-way).
// LDS: Wh 32x560 @0 | Bh 32x560 @17920 -> 35840. grid 512 (8b x 64lt,
// 32-l tiles) = 2 blocks/CU, 256 thr = 4 waves (2mt x 2nt tiles).
__global__ __launch_bounds__(256) void k_uni_res(const _Float16* __restrict__ AO,
    const float* __restrict__ W, const float* __restrict__ bias,
    const float* __restrict__ Xin, float* __restrict__ Y) {
  __shared__ __align__(16) char lds[35840];
  char* Wh = lds;                               // f16 [c][cc], rows 560 B
  char* Bh = lds + 17920;                       // f16 [l][cc], rows 560 B
  int t  = threadIdx.x;
  int bx = blockIdx.x;                          // 512: b(8) x lt(64)
  int lt = bx & 63, b = bx >> 6;
  int l0 = lt * 32;

  // ---- stage W -> f16 [c][cc] (8 f4 per thread, coalesced)
#pragma unroll
  for (int i = 0; i < 8; ++i) {
    int idx = t + i * 256;                      // f4 index; 2048 total
    f4 wv4 = ((const f4*)W)[idx];
    uint2 pk;
    pk.x = __builtin_bit_cast(unsigned, __builtin_amdgcn_cvt_pkrtz(wv4[0], wv4[1]));
    pk.y = __builtin_bit_cast(unsigned, __builtin_amdgcn_cvt_pkrtz(wv4[2], wv4[3]));
    int c = idx >> 6, ccp = idx & 63;           // 64 f4 per 256-cc row
    *(uint2*)(Wh + c * 560 + ccp * 8) = pk;
  }
  // ---- stage AO^T -> Bh[l][cc]: thread (cc=t>>2 per iter, chunk=t&3)
#pragma unroll
  for (int it = 0; it < 4; ++it) {
    int cc = it * 64 + (t >> 2), chunk = t & 3;
    h8 av = *(const h8*)(AO + ((size_t)b * CHH + cc) * LL + l0 + chunk * 8);
#pragma unroll
    for (int e = 0; e < 8; ++e)
      *(_Float16*)(Bh + (chunk * 8 + e) * 560 + cc * 2) = av[e];
  }
  __syncthreads();

  // ---- MFMA: 4 waves, wave w: mt = w>>1 (c half), nt2 = w&1 (l half)
  int wv = t >> 6, lane = t & 63;
  int g = lane >> 4, ln = lane & 15;
  int mt = wv >> 1, nt2 = wv & 1;
  f4 acc = {0.f, 0.f, 0.f, 0.f};
#pragma unroll
  for (int ks = 0; ks < 8; ++ks) {
    h8 af = *(const h8*)(Wh + (mt * 16 + ln) * 560 + (ks * 32 + g * 8) * 2);
    h8 bf = *(const h8*)(Bh + (nt2 * 16 + ln) * 560 + (ks * 32 + g * 8) * 2);
    acc = __builtin_amdgcn_mfma_f32_16x16x32_f16(af, bf, acc, 0, 0, 0);
  }
  // ---- epilogue: c = mt*16+g*4+i, l = l0 + nt2*16 + ln
#pragma unroll
  for (int i = 0; i < 4; ++i) {
    int c = mt * 16 + g * 4 + i;
    size_t o = ((size_t)b * CC + c) * LL + l0 + nt2 * 16 + ln;
    Y[o] = acc[i] + bias[c] + Xin[o];
  }
}

// ---------------------------------------------------------- instance norm
// (R10-verified form: 512 threads, 4 elems/thread.)
__global__ __launch_bounds__(512) void k_inorm(const float* __restrict__ Y,
    float* __restrict__ X, const float* __restrict__ g,
    const float* __restrict__ bt) {
  __shared__ float red[16];
  int row = blockIdx.x;
  int c = row & 31;
  const float* y = Y + (size_t)row * LL;
  float v[4];
  float s = 0.f, ss = 0.f;
#pragma unroll
  for (int i = 0; i < 4; ++i) {
    v[i] = y[threadIdx.x + 512 * i];
    s += v[i];
    ss = fmaf(v[i], v[i], ss);
  }
#pragma unroll
  for (int off = 32; off; off >>= 1) {
    s  += __shfl_down(s, off);
    ss += __shfl_down(ss, off);
  }
  int wid = threadIdx.x >> 6;
  if ((threadIdx.x & 63) == 0) { red[wid * 2] = s; red[wid * 2 + 1] = ss; }
  __syncthreads();
  if (threadIdx.x == 0) {
    float rs0 = 0.f, rs1 = 0.f;
#pragma unroll
    for (int i = 0; i < 8; ++i) { rs0 += red[i * 2]; rs1 += red[i * 2 + 1]; }
    red[0] = rs0; red[1] = rs1;
  }
  __syncthreads();
  float mean = red[0] * (1.f / LL);
  float var  = red[1] * (1.f / LL) - mean * mean;
  float rs = rsqrtf(var + 1e-5f) * g[c];
  float bb = bt[c];
#pragma unroll
  for (int i = 0; i < 4; ++i)
    X[(size_t)row * LL + threadIdx.x + 512 * i] = (v[i] - mean) * rs + bb;
}

// -------- fused FFN v5 (R10-verified): LDS-staged weights, phase-split.
// LDS: wlds 33.3KB + ps 29.6KB = 62.8KB -> 2 blocks/CU.
__global__ __launch_bounds__(256) void k_ffn(const float* __restrict__ X,
    const float* __restrict__ W1, const float* __restrict__ b1,
    const float* __restrict__ W2, const float* __restrict__ b2,
    float* __restrict__ Y) {
  __shared__ __align__(16) float wlds[8320];    // W1 @0, W2 @4096, b1 @8192
  __shared__ float ps[7][32 * 33];
  int bx = blockIdx.x;                          // 8b * 64lt
  int b = bx >> 6;
  int l0 = (bx & 63) * 32;
  int t = threadIdx.x;
  int li = t & 31;
  int og = t >> 5;                              // 0..7
  int l = l0 + li;
  // ---- stage weights to LDS (coalesced f4)
#pragma unroll
  for (int i = 0; i < 4; ++i)
    ((f4*)wlds)[t + i * 256] = ((const f4*)W1)[t + i * 256];
#pragma unroll
  for (int i = 0; i < 4; ++i)
    ((f4*)(wlds + 4096))[t + i * 256] = ((const f4*)W2)[t + i * 256];
  if (t < 32) ((f4*)(wlds + 8192))[t] = ((const f4*)b1)[t];

  const float* Xp = X + (size_t)b * CC * LL + l;
  float xv[32];
#pragma unroll
  for (int c = 0; c < 32; ++c) xv[c] = Xp[(size_t)c * LL];
  __syncthreads();

  // ---- phase A: 16 hidden units, 4-wide partial chains from LDS
  float hs[16];
#pragma unroll
  for (int op = 0; op < 16; ++op) {
    int o = og * 16 + op;
    const f4* wr = (const f4*)(wlds + o * 32);
    f4 p = {wlds[8192 + o], 0.f, 0.f, 0.f};
#pragma unroll
    for (int c4 = 0; c4 < 8; ++c4) {
      f4 a = wr[c4];
      p[0] = fmaf(a[0], xv[c4 * 4 + 0], p[0]);
      p[1] = fmaf(a[1], xv[c4 * 4 + 1], p[1]);
      p[2] = fmaf(a[2], xv[c4 * 4 + 2], p[2]);
      p[3] = fmaf(a[3], xv[c4 * 4 + 3], p[3]);
    }
    hs[op] = fmaxf((p[0] + p[1]) + (p[2] + p[3]), 0.f);
  }

  // ---- phase B: 32 outputs, f4 W2 reads from LDS
  float acc[32];
#pragma unroll
  for (int c = 0; c < 32; ++c) {
    const f4* w2r = (const f4*)(wlds + 4096 + c * 128 + og * 16);
    f4 s = {0.f, 0.f, 0.f, 0.f};
#pragma unroll
    for (int o4 = 0; o4 < 4; ++o4) {
      f4 w = w2r[o4];
      s[0] = fmaf(w[0], hs[o4 * 4 + 0], s[0]);
      s[1] = fmaf(w[1], hs[o4 * 4 + 1], s[1]);
      s[2] = fmaf(w[2], hs[o4 * 4 + 2], s[2]);
      s[3] = fmaf(w[3], hs[o4 * 4 + 3], s[3]);
    }
    acc[c] = (s[0] + s[1]) + (s[2] + s[3]);
  }

  if (og) {
#pragma unroll
    for (int c = 0; c < 32; ++c) ps[og - 1][li * 33 + c] = acc[c];
  }
  __syncthreads();
  if (!og) {
    float* Yp = Y + (size_t)b * CC * LL + l;
#pragma unroll
    for (int c = 0; c < 32; ++c) {
      float r = acc[c] + b2[c] + xv[c];
#pragma unroll
      for (int q = 0; q < 7; ++q) r += ps[q][li * 33 + c];
      Yp[(size_t)c * LL] = r;
    }
  }
}

// ------------------------------------------------------------- classifier
__global__ __launch_bounds__(256) void k_cls(const float* __restrict__ X,
    const float* __restrict__ W, const float* __restrict__ bias,
    float* __restrict__ out) {
  int idx = blockIdx.x * 256 + threadIdx.x;
  int l = idx & (LL - 1);
  int b = idx >> 11;
  float s = bias[0];
#pragma unroll
  for (int c = 0; c < CC; ++c)
    s = fmaf(W[c], X[((size_t)b * CC + c) * LL + l], s);
  out[idx] = 1.f / (1.f + __expf(-s));
}

// ------------------------------------------------------------------ launch
extern "C" void kernel_launch(void* const* d_in, const int* in_sizes, int n_in,
                              void* d_out, int out_size, void* d_ws,
                              size_t ws_size, hipStream_t stream) {
  const float* x      = (const float*)d_in[0];
  const float* enc_W  = (const float*)d_in[1];
  const float* enc_b  = (const float*)d_in[2];
  const float* pw_q   = (const float*)d_in[3];
  const float* dw3_q  = (const float*)d_in[4];
  const float* dw15_q = (const float*)d_in[5];
  const float* gate_q = (const float*)d_in[6];
  const float* pw_k   = (const float*)d_in[7];
  const float* dw3_k  = (const float*)d_in[8];
  const float* dw15_k = (const float*)d_in[9];
  const float* gate_k = (const float*)d_in[10];
  const float* pw_v   = (const float*)d_in[11];
  const float* dw3_v  = (const float*)d_in[12];
  const float* dw15_v = (const float*)d_in[13];
  const float* gate_v = (const float*)d_in[14];
  const float* uni_W  = (const float*)d_in[15];
  const float* uni_b  = (const float*)d_in[16];
  const float* n1_g   = (const float*)d_in[17];
  const float* n1_b   = (const float*)d_in[18];
  const float* n2_g   = (const float*)d_in[19];
  const float* n2_b   = (const float*)d_in[20];
  const float* ffn_W1 = (const float*)d_in[21];
  const float* ffn_b1 = (const float*)d_in[22];
  const float* ffn_W2 = (const float*)d_in[23];
  const float* ffn_b2 = (const float*)d_in[24];
  const float* cls_W  = (const float*)d_in[25];
  const float* cls_b  = (const float*)d_in[26];

  float* ws = (float*)d_ws;
  float* X   = ws;                             // [B,32,L] fp32
  float* Y   = ws + 524288;                    // [B,32,L] fp32
  _Float16* AO = (_Float16*)(ws + 1048576);    // [B,256,L] f16 attn out
  _Float16* Qt = (_Float16*)(ws + 9437184);    // [64bh][L][32c] f16
  _Float16* Kt = (_Float16*)(ws + 11534336);   // [64bh][L][32c] f16
  _Float16* Vt = (_Float16*)(ws + 13631488);   // [64bh][32c][L] f16

  k_enc<<<2048, 256, 0, stream>>>(x, enc_W, enc_b, X);

  for (int d = 0; d < DD; ++d) {
    k_qkv<<<dim3(1024, 3), 256, 0, stream>>>(X,
        pw_q + d * CHH * CC, pw_k + d * CHH * CC, pw_v + d * CHH * CC,
        dw3_q + d * CHH * 3, dw15_q + d * CHH * 15, gate_q + d * 2,
        dw3_k + d * CHH * 3, dw15_k + d * CHH * 15, gate_k + d * 2,
        dw3_v + d * CHH * 3, dw15_v + d * CHH * 15, gate_v + d * 2,
        Qt, Kt, Vt);
    k_attn<<<dim3(16, 64), 512, 0, stream>>>(Qt, Kt, Vt, AO);
    k_uni_res<<<512, 256, 0, stream>>>(AO, uni_W + d * CC * CHH,
                                       uni_b + d * CC, X, Y);
    k_inorm<<<256, 512, 0, stream>>>(Y, X, n1_g + d * CC, n1_b + d * CC);
    k_ffn<<<512, 256, 0, stream>>>(X, ffn_W1 + d * 128 * CC, ffn_b1 + d * 128,
                                   ffn_W2 + d * CC * 128, ffn_b2 + d * CC, Y);
    k_inorm<<<256, 512, 0, stream>>>(Y, X, n2_g + d * CC, n2_b + d * CC);
  }

  k_cls<<<64, 256, 0, stream>>>(X, cls_W, cls_b, (float*)d_out);
}

// Round 18
// 609.694 us; speedup vs baseline: 1.4930x; 1.0881x over previous
//
#include <hip/hip_runtime.h>
#include <math.h>

#define LL   2048
#define BB   8
#define CC   32
#define CHH  256
#define HH   8
#define DD   6

typedef _Float16 h8 __attribute__((ext_vector_type(8)));
typedef _Float16 h4 __attribute__((ext_vector_type(4)));
typedef float f4 __attribute__((ext_vector_type(4)));
typedef float f2v __attribute__((ext_vector_type(2)));

// ---------------------------------------------------------------- encoder
__global__ __launch_bounds__(256) void k_enc(const float* __restrict__ x,
    const float* __restrict__ W, const float* __restrict__ bias,
    float* __restrict__ X) {
  int idx = blockIdx.x * 256 + threadIdx.x;          // B*32*L = 524288
  int l = idx & (LL - 1);
  int c = (idx >> 11) & 31;
  int b = idx >> 16;
  float s = bias[c];
#pragma unroll
  for (int i = 0; i < 6; ++i)
    s = fmaf(W[c * 6 + i], x[((size_t)b * 6 + i) * LL + l], s);
  X[idx] = s;
}

// ------------- fused QKV v2 (R16-verified): MFMA pointwise conv + depthwise
// conv3/conv15 + gate + cvt + layout. 18 mfma 16x16x32 tiles; ~45 LDS
// ops/lane (was 320). LDS: Xh @0 | Wh @9728 | o_tile @11776 -> 21504.
// grid (1024 = bh*16+lt, 3 z), 256 thr.
__global__ __launch_bounds__(256) void k_qkv(const float* __restrict__ X,
    const float* __restrict__ pwq, const float* __restrict__ pwk,
    const float* __restrict__ pwv,
    const float* __restrict__ d3q, const float* __restrict__ d15q, const float* __restrict__ gq,
    const float* __restrict__ d3k, const float* __restrict__ d15k, const float* __restrict__ gk,
    const float* __restrict__ d3v, const float* __restrict__ d15v, const float* __restrict__ gv,
    _Float16* __restrict__ Qt, _Float16* __restrict__ Kt, _Float16* __restrict__ Vt) {
  __shared__ __align__(16) char lds[21504];
  int z  = blockIdx.y;
  int bx = blockIdx.x;
  int bh = bx >> 4, lt = bx & 15, l0 = lt * 128;
  int b = bh >> 3, h = bh & 7;
  int t = threadIdx.x;
  const float* pwp  = (z == 0) ? pwq  : (z == 1) ? pwk  : pwv;
  const float* w3p  = (z == 0) ? d3q  : (z == 1) ? d3k  : d3v;
  const float* w15p = (z == 0) ? d15q : (z == 1) ? d15k : d15v;
  const float* gp   = (z == 0) ? gq   : (z == 1) ? gk   : gv;

  char* Xh = lds;                              // f16 [32 ci][152 m] rows 304B
  char* Wh = lds + 9728;                       // f16 [32 r][32 ci] rows 64B
  char* ot = lds + 11776;                      // pw out f16, 32 x 304B

  // ---- stage X -> f16 [ci][m], m = l-(l0-8) in [0,144), OOB zero
  {
    int r = t >> 3, u = t & 7;
    const float* xr = X + ((size_t)b * CC + r) * LL;
    char* xd = Xh + r * 304;
#pragma unroll
    for (int s = u; s < 36; s += 8) {
      int ls = l0 - 8 + s * 4;
      f4 v;
      if (ls >= 0 && ls + 3 < LL) {
        v = *(const f4*)(xr + ls);
      } else {
#pragma unroll
        for (int e = 0; e < 4; ++e) {
          int l = ls + e;
          v[e] = (l >= 0 && l < LL) ? xr[l] : 0.f;
        }
      }
      uint2 pk;
      pk.x = __builtin_bit_cast(unsigned, __builtin_amdgcn_cvt_pkrtz(v[0], v[1]));
      pk.y = __builtin_bit_cast(unsigned, __builtin_amdgcn_cvt_pkrtz(v[2], v[3]));
      *(uint2*)(xd + s * 8) = pk;
    }
  }
  // ---- stage W -> f16 [r][ci]
  {
    f4 wg = ((const f4*)(pwp + h * 1024))[t];  // och = t>>3, ci0 = (t&7)*4
    uint2 pk;
    pk.x = __builtin_bit_cast(unsigned, __builtin_amdgcn_cvt_pkrtz(wg[0], wg[1]));
    pk.y = __builtin_bit_cast(unsigned, __builtin_amdgcn_cvt_pkrtz(wg[2], wg[3]));
    *(uint2*)(Wh + (t >> 3) * 64 + (t & 7) * 8) = pk;
  }
  __syncthreads();

  // ---- phase 1: pointwise conv as MFMA.  out[r][m] = sum_ci W[r][ci]X[ci][m]
  {
    int w4 = t >> 6, lane = t & 63;
    int g = lane >> 4, ln = lane & 15;
    h8 af[2];
#pragma unroll
    for (int mt = 0; mt < 2; ++mt)
      af[mt] = *(const h8*)(Wh + (mt * 16 + ln) * 64 + g * 16);
    for (int nt = w4; nt < 9; nt += 4) {
      h8 bf;
#pragma unroll
      for (int j = 0; j < 8; ++j)
        bf[j] = *(const _Float16*)(Xh + (g * 8 + j) * 304 + (nt * 16 + ln) * 2);
#pragma unroll
      for (int mt = 0; mt < 2; ++mt) {
        f4 zr = {0.f, 0.f, 0.f, 0.f};
        f4 d = __builtin_amdgcn_mfma_f32_16x16x32_f16(af[mt], bf, zr, 0, 0, 0);
#pragma unroll
        for (int i = 0; i < 4; ++i)
          *(_Float16*)(ot + (mt * 16 + g * 4 + i) * 304 + (nt * 16 + ln) * 2) =
              (_Float16)d[i];
      }
    }
  }
  __syncthreads();

  // ---- phase 2: depthwise conv3 + conv15 + softmax gate (unchanged)
  int c = t & 31, cg = t >> 5;
  float wv[32];
  {
    const h8* wp = (const h8*)(ot + c * 304 + cg * 32);
#pragma unroll
    for (int q4 = 0; q4 < 4; ++q4) {
      h8 v = wp[q4];
#pragma unroll
      for (int e = 0; e < 8; ++e) wv[q4 * 8 + e] = (float)v[e];
    }
  }
  float r0 = gp[0], r1 = gp[1];
  float mx = fmaxf(r0, r1);
  float e0 = __expf(r0 - mx), e1 = __expf(r1 - mx);
  float gi = 1.f / (e0 + e1);
  float g0 = e0 * gi, g1 = e1 * gi;
  float sc = (z == 0) ? 0.2550765737f : 1.0f;   // C^-0.5 * log2(e) fold
  int ch = h * 32 + c;
  float w3r[3], w15r[15];
#pragma unroll
  for (int k = 0; k < 3; ++k)  w3r[k]  = w3p[ch * 3 + k];
#pragma unroll
  for (int k = 0; k < 15; ++k) w15r[k] = w15p[ch * 15 + k];

  h8 olo, ohi;
#pragma unroll
  for (int i = 0; i < 16; ++i) {
    float a = 0.f;
#pragma unroll
    for (int k = 0; k < 3; ++k) a = fmaf(w3r[k], wv[i + 7 + k], a);
    float s15 = 0.f;
#pragma unroll
    for (int k = 0; k < 15; ++k) s15 = fmaf(w15r[k], wv[i + 1 + k], s15);
    float val = (g0 * a + g1 * s15) * sc;
    if (i < 8) olo[i] = (_Float16)val; else ohi[i - 8] = (_Float16)val;
  }

  if (z == 2) {
    _Float16* dst = Vt + ((size_t)bh * 32 + c) * LL + l0 + cg * 16;
    *(h8*)dst = olo;
    *(h8*)(dst + 8) = ohi;
  } else {
    char* tb = lds;                             // reuse Xh region (dead)
    __syncthreads();
#pragma unroll
    for (int i = 0; i < 16; ++i) {
      _Float16 v = (i < 8) ? olo[i] : ohi[i - 8];
      *(_Float16*)(tb + (cg * 16 + i) * 80 + c * 2) = v;
    }
    __syncthreads();
    _Float16* dst = ((z == 0) ? Qt : Kt) + ((size_t)bh * LL + l0) * 32;
    int l = t >> 1, hf = t & 1;
    uint4 a = *(uint4*)(tb + l * 80 + hf * 32);
    uint4 b2 = *(uint4*)(tb + l * 80 + hf * 32 + 16);
    *(uint4*)(dst + (size_t)l * 32 + hf * 16) = a;
    *(uint4*)(dst + (size_t)l * 32 + hf * 16 + 8) = b2;
  }
}

// ------------------------------------------------ MFMA flash attention (f16)
// R14-verified: XCD-aware block swizzle (FETCH 69.7->12.3 MB confirmed) +
// R4/R6 core: 8 waves, key-split, dbuf LDS, native exp2, permlane PV
// fragment, in-LDS merge.
__global__ __launch_bounds__(512, 2) void k_attn(
    const _Float16* __restrict__ Qt, const _Float16* __restrict__ Kt,
    const _Float16* __restrict__ Vt, _Float16* __restrict__ AO) {
  __shared__ __align__(16) char lds[38912];
  const int tid  = threadIdx.x;
  const int lane = tid & 63;
  const int w    = tid >> 6;                   // 0..7
  const int seg  = w >> 2;                     // 0..1: key segment
  const int wq   = w & 3;                      // q sub-block within 128
  const int g    = lane >> 4;
  const int ln   = lane & 15;
  const int h2c  = (wq >> 1) * 2;
  const int lin  = blockIdx.x + (blockIdx.y << 4);        // 0..1023
  const int swz  = ((lin & 7) << 7) | (lin >> 3);         // XCD-grouped
  const int qb   = swz & 15;                   // 0..15
  const int bh   = swz >> 4;                   // 0..63
  const _Float16* Qg = Qt + ((size_t)bh * LL + qb * 128) * 32;
  const _Float16* Kg = Kt + ((size_t)bh * LL + seg * 1024) * 32;
  const _Float16* Vg = Vt + (size_t)bh * 32 * LL + seg * 1024;

  h8 qf[2];
#pragma unroll
  for (int nt = 0; nt < 2; ++nt)
    qf[nt] = *(const h8*)(Qg + (size_t)(wq * 32 + nt * 16 + ln) * 32 + g * 8);

  h8 ones;
#pragma unroll
  for (int j = 0; j < 8; ++j) ones[j] = (_Float16)1.0f;

  char* kb = lds + seg * 5120;                 // + p*10240
  char* vb = lds + 20480 + seg * 4608;         // + p*9216

  uint4 stg0, stg1;
  if ((wq & 1) == 0) {
    const uint4* gk = (const uint4*)Kg;
    stg0 = gk[h2c * 64 + lane];
    stg1 = gk[(h2c + 1) * 64 + lane];
    *(uint4*)(kb + (h2c * 16 + (lane >> 2)) * 80 + (lane & 3) * 16) = stg0;
    *(uint4*)(kb + ((h2c + 1) * 16 + (lane >> 2)) * 80 + (lane & 3) * 16) = stg1;
  } else {
    int c0 = h2c * 8 + (lane >> 3);
    stg0 = *(const uint4*)(Vg + (size_t)c0 * LL + (lane & 7) * 8);
    stg1 = *(const uint4*)(Vg + (size_t)(c0 + 8) * LL + (lane & 7) * 8);
    *(uint4*)(vb + c0 * 144 + (lane & 7) * 16) = stg0;
    *(uint4*)(vb + (c0 + 8) * 144 + (lane & 7) * 16) = stg1;
  }
  __syncthreads();

  f4 o[2][2];
#pragma unroll
  for (int ct = 0; ct < 2; ++ct)
#pragma unroll
    for (int nt = 0; nt < 2; ++nt) o[ct][nt] = (f4){0.f, 0.f, 0.f, 0.f};
  f4 sacc[2];
#pragma unroll
  for (int nt = 0; nt < 2; ++nt) sacc[nt] = (f4){0.f, 0.f, 0.f, 0.f};

  for (int it = 0; it < 16; ++it) {
    int pp = it & 1;
    char* kbc = kb + pp * 10240;
    char* vbc = vb + pp * 9216;
    if (it < 15) {
      int k0n = (it + 1) * 64;
      if ((wq & 1) == 0) {
        const uint4* gk = (const uint4*)(Kg + (size_t)k0n * 32);
        stg0 = gk[h2c * 64 + lane];
        stg1 = gk[(h2c + 1) * 64 + lane];
      } else {
        int c0 = h2c * 8 + (lane >> 3);
        stg0 = *(const uint4*)(Vg + (size_t)c0 * LL + k0n + (lane & 7) * 8);
        stg1 = *(const uint4*)(Vg + (size_t)(c0 + 8) * LL + k0n + (lane & 7) * 8);
      }
    }
#pragma unroll
    for (int chunk = 0; chunk < 2; ++chunk) {
      unsigned pa[2][2], pb[2][2];
#pragma unroll
      for (int mt2 = 0; mt2 < 2; ++mt2) {
        h8 kf = *(const h8*)(kbc + ((chunk * 2 + mt2) * 16 + ln) * 80 + g * 16);
#pragma unroll
        for (int nt = 0; nt < 2; ++nt) {
          f4 z = {0.f, 0.f, 0.f, 0.f};
          f4 s = __builtin_amdgcn_mfma_f32_16x16x32_f16(kf, qf[nt], z, 0, 0, 0);
          float p0 = __builtin_amdgcn_exp2f(s[0]);
          float p1 = __builtin_amdgcn_exp2f(s[1]);
          float p2 = __builtin_amdgcn_exp2f(s[2]);
          float p3 = __builtin_amdgcn_exp2f(s[3]);
          unsigned lo = __builtin_bit_cast(unsigned,
              __builtin_amdgcn_cvt_pkrtz(p0, p1));
          unsigned hi = __builtin_bit_cast(unsigned,
              __builtin_amdgcn_cvt_pkrtz(p2, p3));
          if (mt2 == 0) { pa[nt][0] = lo; pa[nt][1] = hi; }
          else          { pb[nt][0] = lo; pb[nt][1] = hi; }
        }
      }
      h8 vf[2];
#pragma unroll
      for (int ct = 0; ct < 2; ++ct)
        vf[ct] = *(const h8*)(vbc + (ct * 16 + ln) * 144 + chunk * 64 + g * 16);
#pragma unroll
      for (int nt = 0; nt < 2; ++nt) {
        unsigned w0 = pa[nt][0], w1 = pa[nt][1];
        unsigned w2 = pb[nt][0], w3 = pb[nt][1];
        asm("v_permlane32_swap_b32 %0, %1" : "+v"(w0), "+v"(w2));
        asm("v_permlane16_swap_b32 %0, %1" : "+v"(w0), "+v"(w2));
        asm("v_permlane32_swap_b32 %0, %1" : "+v"(w1), "+v"(w3));
        asm("v_permlane16_swap_b32 %0, %1" : "+v"(w1), "+v"(w3));
        uint4 pw4; pw4.x = w0; pw4.y = w1; pw4.z = w2; pw4.w = w3;
        h8 pf = __builtin_bit_cast(h8, pw4);
        sacc[nt] = __builtin_amdgcn_mfma_f32_16x16x32_f16(ones, pf, sacc[nt], 0, 0, 0);
        o[0][nt] = __builtin_amdgcn_mfma_f32_16x16x32_f16(vf[0], pf, o[0][nt], 0, 0, 0);
        o[1][nt] = __builtin_amdgcn_mfma_f32_16x16x32_f16(vf[1], pf, o[1][nt], 0, 0, 0);
      }
    }
    if (it < 15) {
      char* kbn = kb + (pp ^ 1) * 10240;
      char* vbn = vb + (pp ^ 1) * 9216;
      if ((wq & 1) == 0) {
        *(uint4*)(kbn + (h2c * 16 + (lane >> 2)) * 80 + (lane & 3) * 16) = stg0;
        *(uint4*)(kbn + ((h2c + 1) * 16 + (lane >> 2)) * 80 + (lane & 3) * 16) = stg1;
      } else {
        int c0 = h2c * 8 + (lane >> 3);
        *(uint4*)(vbn + c0 * 144 + (lane & 7) * 16) = stg0;
        *(uint4*)(vbn + (c0 + 8) * 144 + (lane & 7) * 16) = stg1;
      }
    }
    __syncthreads();
  }

  if (seg == 1) {
    char* eo = lds + wq * 9216 + lane * 144;
#pragma unroll
    for (int nt = 0; nt < 2; ++nt)
#pragma unroll
      for (int ct = 0; ct < 2; ++ct)
        *(f4*)(eo + (nt * 2 + ct) * 16) = o[ct][nt];
    f4 sv;
    sv[0] = sacc[0][0]; sv[1] = sacc[1][0];
    sv[2] = 0.f; sv[3] = 0.f;
    *(f4*)(eo + 64) = sv;
  }
  __syncthreads();
  if (seg == 0) {
    const char* po = lds + wq * 9216 + lane * 144;
    f4 s1v = *(const f4*)(po + 64);
    _Float16* out = AO + (size_t)bh * (32 * LL);
#pragma unroll
    for (int nt = 0; nt < 2; ++nt) {
      float inv = 1.f / (sacc[nt][0] + s1v[nt]);
      int qg = qb * 128 + wq * 32 + nt * 16 + ln;
#pragma unroll
      for (int ct = 0; ct < 2; ++ct) {
        f4 o1 = *(const f4*)(po + (nt * 2 + ct) * 16);
#pragma unroll
        for (int r = 0; r < 4; ++r)
          out[(size_t)(ct * 16 + g * 4 + r) * LL + qg] =
              (_Float16)((o[ct][nt][r] + o1[r]) * inv);
      }
    }
  }
}

// -------- uni GEMM v6 (R17-verified): MFMA. A = W f16, B = AO^T via LDS
// transpose, 8 k-steps mfma 16x16x32, D-fragment epilogue with bias+residual.
// LDS: Wh 32x560 @0 | Bh 32x560 @17920 -> 35840. grid 512, 4 waves.
__global__ __launch_bounds__(256) void k_uni_res(const _Float16* __restrict__ AO,
    const float* __restrict__ W, const float* __restrict__ bias,
    const float* __restrict__ Xin, float* __restrict__ Y) {
  __shared__ __align__(16) char lds[35840];
  char* Wh = lds;                               // f16 [c][cc], rows 560 B
  char* Bh = lds + 17920;                       // f16 [l][cc], rows 560 B
  int t  = threadIdx.x;
  int bx = blockIdx.x;                          // 512: b(8) x lt(64)
  int lt = bx & 63, b = bx >> 6;
  int l0 = lt * 32;

#pragma unroll
  for (int i = 0; i < 8; ++i) {
    int idx = t + i * 256;                      // f4 index; 2048 total
    f4 wv4 = ((const f4*)W)[idx];
    uint2 pk;
    pk.x = __builtin_bit_cast(unsigned, __builtin_amdgcn_cvt_pkrtz(wv4[0], wv4[1]));
    pk.y = __builtin_bit_cast(unsigned, __builtin_amdgcn_cvt_pkrtz(wv4[2], wv4[3]));
    int c = idx >> 6, ccp = idx & 63;
    *(uint2*)(Wh + c * 560 + ccp * 8) = pk;
  }
#pragma unroll
  for (int it = 0; it < 4; ++it) {
    int cc = it * 64 + (t >> 2), chunk = t & 3;
    h8 av = *(const h8*)(AO + ((size_t)b * CHH + cc) * LL + l0 + chunk * 8);
#pragma unroll
    for (int e = 0; e < 8; ++e)
      *(_Float16*)(Bh + (chunk * 8 + e) * 560 + cc * 2) = av[e];
  }
  __syncthreads();

  int wv = t >> 6, lane = t & 63;
  int g = lane >> 4, ln = lane & 15;
  int mt = wv >> 1, nt2 = wv & 1;
  f4 acc = {0.f, 0.f, 0.f, 0.f};
#pragma unroll
  for (int ks = 0; ks < 8; ++ks) {
    h8 af = *(const h8*)(Wh + (mt * 16 + ln) * 560 + (ks * 32 + g * 8) * 2);
    h8 bf = *(const h8*)(Bh + (nt2 * 16 + ln) * 560 + (ks * 32 + g * 8) * 2);
    acc = __builtin_amdgcn_mfma_f32_16x16x32_f16(af, bf, acc, 0, 0, 0);
  }
#pragma unroll
  for (int i = 0; i < 4; ++i) {
    int c = mt * 16 + g * 4 + i;
    size_t o = ((size_t)b * CC + c) * LL + l0 + nt2 * 16 + ln;
    Y[o] = acc[i] + bias[c] + Xin[o];
  }
}

// ---------------------------------------------------------- instance norm
// (R10-verified form: 512 threads, 4 elems/thread.)
__global__ __launch_bounds__(512) void k_inorm(const float* __restrict__ Y,
    float* __restrict__ X, const float* __restrict__ g,
    const float* __restrict__ bt) {
  __shared__ float red[16];
  int row = blockIdx.x;
  int c = row & 31;
  const float* y = Y + (size_t)row * LL;
  float v[4];
  float s = 0.f, ss = 0.f;
#pragma unroll
  for (int i = 0; i < 4; ++i) {
    v[i] = y[threadIdx.x + 512 * i];
    s += v[i];
    ss = fmaf(v[i], v[i], ss);
  }
#pragma unroll
  for (int off = 32; off; off >>= 1) {
    s  += __shfl_down(s, off);
    ss += __shfl_down(ss, off);
  }
  int wid = threadIdx.x >> 6;
  if ((threadIdx.x & 63) == 0) { red[wid * 2] = s; red[wid * 2 + 1] = ss; }
  __syncthreads();
  if (threadIdx.x == 0) {
    float rs0 = 0.f, rs1 = 0.f;
#pragma unroll
    for (int i = 0; i < 8; ++i) { rs0 += red[i * 2]; rs1 += red[i * 2 + 1]; }
    red[0] = rs0; red[1] = rs1;
  }
  __syncthreads();
  float mean = red[0] * (1.f / LL);
  float var  = red[1] * (1.f / LL) - mean * mean;
  float rs = rsqrtf(var + 1e-5f) * g[c];
  float bb = bt[c];
#pragma unroll
  for (int i = 0; i < 4; ++i)
    X[(size_t)row * LL + threadIdx.x + 512 * i] = (v[i] - mean) * rs + bb;
}

// -------- fused FFN v6: both GEMMs on MFMA (R18, same G10 lever as R16/R17).
// Phase A: h[128o][32l] = W1 x X^T (16 tiles, k=32 one step), +b1, relu on
// f32 D-fragment, fragment-scatter into Hh[l][o] (free transpose).
// Phase B: out[32c][32l] = W2 x h (4 tiles x 4 k-steps), +b2 + residual.
// Rows padded to 16B multiples (80/272 B: stride 20/4 banks -> <=2-way, free).
// LDS: Xh 32x80 @0 | W1h 128x80 @2560 | W2h 32x272 @12800 | Hh 32x272
// @21504 | b1h 128f @30208 -> 30720. grid 512 (8b x 64lt) = 2 blocks/CU.
__global__ __launch_bounds__(256) void k_ffn(const float* __restrict__ X,
    const float* __restrict__ W1, const float* __restrict__ b1,
    const float* __restrict__ W2, const float* __restrict__ b2,
    float* __restrict__ Y) {
  __shared__ __align__(16) char lds[30720];
  char* Xh  = lds;                              // f16 [l][c]  rows 80 B
  char* W1h = lds + 2560;                       // f16 [o][c]  rows 80 B
  char* W2h = lds + 12800;                      // f16 [c][o]  rows 272 B
  char* Hh  = lds + 21504;                      // f16 [l][o]  rows 272 B
  float* b1h = (float*)(lds + 30208);           // 128 f32
  int t  = threadIdx.x;
  int bx = blockIdx.x;                          // 8b x 64lt
  int lt = bx & 63, b = bx >> 6;
  int l0 = lt * 32;

  // ---- stage X^T -> f16 [l][c]: c = t>>3, le0 = (t&7)*4
  {
    int c = t >> 3, le0 = (t & 7) * 4;
    f4 v = *(const f4*)(X + ((size_t)b * CC + c) * LL + l0 + le0);
#pragma unroll
    for (int e = 0; e < 4; ++e)
      *(_Float16*)(Xh + (le0 + e) * 80 + c * 2) = (_Float16)v[e];
  }
  // ---- stage W1 -> f16 [o][c] (4 f4/thread)
#pragma unroll
  for (int i = 0; i < 4; ++i) {
    int idx = t + i * 256;                      // 1024 f4 total
    f4 wv4 = ((const f4*)W1)[idx];
    uint2 pk;
    pk.x = __builtin_bit_cast(unsigned, __builtin_amdgcn_cvt_pkrtz(wv4[0], wv4[1]));
    pk.y = __builtin_bit_cast(unsigned, __builtin_amdgcn_cvt_pkrtz(wv4[2], wv4[3]));
    int o = idx >> 3, cp = idx & 7;             // 8 f4 per 32-c row
    *(uint2*)(W1h + o * 80 + cp * 8) = pk;
  }
  // ---- stage W2 -> f16 [c][o] (4 f4/thread)
#pragma unroll
  for (int i = 0; i < 4; ++i) {
    int idx = t + i * 256;                      // 1024 f4 total
    f4 wv4 = ((const f4*)W2)[idx];
    uint2 pk;
    pk.x = __builtin_bit_cast(unsigned, __builtin_amdgcn_cvt_pkrtz(wv4[0], wv4[1]));
    pk.y = __builtin_bit_cast(unsigned, __builtin_amdgcn_cvt_pkrtz(wv4[2], wv4[3]));
    int c = idx >> 5, op = idx & 31;            // 32 f4 per 128-o row
    *(uint2*)(W2h + c * 272 + op * 8) = pk;
  }
  if (t < 128) b1h[t] = b1[t];
  __syncthreads();

  int w4 = t >> 6, lane = t & 63;
  int g = lane >> 4, ln = lane & 15;

  // ---- phase A: 16 tiles (8 ot x 2 lt2); wave w4 does ti = w4*4+j
#pragma unroll
  for (int j = 0; j < 4; ++j) {
    int ti = w4 * 4 + j;
    int ot = ti >> 1, lt2 = ti & 1;
    h8 af = *(const h8*)(W1h + (ot * 16 + ln) * 80 + g * 16);
    h8 bf = *(const h8*)(Xh + (lt2 * 16 + ln) * 80 + g * 16);
    f4 zr = {0.f, 0.f, 0.f, 0.f};
    f4 d = __builtin_amdgcn_mfma_f32_16x16x32_f16(af, bf, zr, 0, 0, 0);
#pragma unroll
    for (int i = 0; i < 4; ++i) {
      int o = ot * 16 + g * 4 + i;
      float hv = fmaxf(d[i] + b1h[o], 0.f);
      *(_Float16*)(Hh + (lt2 * 16 + ln) * 272 + o * 2) = (_Float16)hv;
    }
  }
  __syncthreads();

  // ---- phase B: 4 tiles (2 ct2 x 2 lt2b), 4 k-steps each
  int ct2 = w4 >> 1, lt2b = w4 & 1;
  f4 acc = {0.f, 0.f, 0.f, 0.f};
#pragma unroll
  for (int ks = 0; ks < 4; ++ks) {
    h8 af = *(const h8*)(W2h + (ct2 * 16 + ln) * 272 + (ks * 32 + g * 8) * 2);
    h8 bf = *(const h8*)(Hh + (lt2b * 16 + ln) * 272 + (ks * 32 + g * 8) * 2);
    acc = __builtin_amdgcn_mfma_f32_16x16x32_f16(af, bf, acc, 0, 0, 0);
  }
#pragma unroll
  for (int i = 0; i < 4; ++i) {
    int c = ct2 * 16 + g * 4 + i;
    size_t o = ((size_t)b * CC + c) * LL + l0 + lt2b * 16 + ln;
    Y[o] = acc[i] + b2[c] + X[o];
  }
}

// ------------------------------------------------------------- classifier
__global__ __launch_bounds__(256) void k_cls(const float* __restrict__ X,
    const float* __restrict__ W, const float* __restrict__ bias,
    float* __restrict__ out) {
  int idx = blockIdx.x * 256 + threadIdx.x;
  int l = idx & (LL - 1);
  int b = idx >> 11;
  float s = bias[0];
#pragma unroll
  for (int c = 0; c < CC; ++c)
    s = fmaf(W[c], X[((size_t)b * CC + c) * LL + l], s);
  out[idx] = 1.f / (1.f + __expf(-s));
}

// ------------------------------------------------------------------ launch
extern "C" void kernel_launch(void* const* d_in, const int* in_sizes, int n_in,
                              void* d_out, int out_size, void* d_ws,
                              size_t ws_size, hipStream_t stream) {
  const float* x      = (const float*)d_in[0];
  const float* enc_W  = (const float*)d_in[1];
  const float* enc_b  = (const float*)d_in[2];
  const float* pw_q   = (const float*)d_in[3];
  const float* dw3_q  = (const float*)d_in[4];
  const float* dw15_q = (const float*)d_in[5];
  const float* gate_q = (const float*)d_in[6];
  const float* pw_k   = (const float*)d_in[7];
  const float* dw3_k  = (const float*)d_in[8];
  const float* dw15_k = (const float*)d_in[9];
  const float* gate_k = (const float*)d_in[10];
  const float* pw_v   = (const float*)d_in[11];
  const float* dw3_v  = (const float*)d_in[12];
  const float* dw15_v = (const float*)d_in[13];
  const float* gate_v = (const float*)d_in[14];
  const float* uni_W  = (const float*)d_in[15];
  const float* uni_b  = (const float*)d_in[16];
  const float* n1_g   = (const float*)d_in[17];
  const float* n1_b   = (const float*)d_in[18];
  const float* n2_g   = (const float*)d_in[19];
  const float* n2_b   = (const float*)d_in[20];
  const float* ffn_W1 = (const float*)d_in[21];
  const float* ffn_b1 = (const float*)d_in[22];
  const float* ffn_W2 = (const float*)d_in[23];
  const float* ffn_b2 = (const float*)d_in[24];
  const float* cls_W  = (const float*)d_in[25];
  const float* cls_b  = (const float*)d_in[26];

  float* ws = (float*)d_ws;
  float* X   = ws;                             // [B,32,L] fp32
  float* Y   = ws + 524288;                    // [B,32,L] fp32
  _Float16* AO = (_Float16*)(ws + 1048576);    // [B,256,L] f16 attn out
  _Float16* Qt = (_Float16*)(ws + 9437184);    // [64bh][L][32c] f16
  _Float16* Kt = (_Float16*)(ws + 11534336);   // [64bh][L][32c] f16
  _Float16* Vt = (_Float16*)(ws + 13631488);   // [64bh][32c][L] f16

  k_enc<<<2048, 256, 0, stream>>>(x, enc_W, enc_b, X);

  for (int d = 0; d < DD; ++d) {
    k_qkv<<<dim3(1024, 3), 256, 0, stream>>>(X,
        pw_q + d * CHH * CC, pw_k + d * CHH * CC, pw_v + d * CHH * CC,
        dw3_q + d * CHH * 3, dw15_q + d * CHH * 15, gate_q + d * 2,
        dw3_k + d * CHH * 3, dw15_k + d * CHH * 15, gate_k + d * 2,
        dw3_v + d * CHH * 3, dw15_v + d * CHH * 15, gate_v + d * 2,
        Qt, Kt, Vt);
    k_attn<<<dim3(16, 64), 512, 0, stream>>>(Qt, Kt, Vt, AO);
    k_uni_res<<<512, 256, 0, stream>>>(AO, uni_W + d * CC * CHH,
                                       uni_b + d * CC, X, Y);
    k_inorm<<<256, 512, 0, stream>>>(Y, X, n1_g + d * CC, n1_b + d * CC);
    k_ffn<<<512, 256, 0, stream>>>(X, ffn_W1 + d * 128 * CC, ffn_b1 + d * 128,
                                   ffn_W2 + d * CC * 128, ffn_b2 + d * CC, Y);
    k_inorm<<<256, 512, 0, stream>>>(Y, X, n2_g + d * CC, n2_b + d * CC);
  }

  k_cls<<<64, 256, 0, stream>>>(X, cls_W, cls_b, (float*)d_out);
}